// Round 6
// baseline (113515.588 us; speedup 1.0000x reference)
//
#include <hip/hip_runtime.h>
#include <hip/hip_cooperative_groups.h>

namespace cg = cooperative_groups;

typedef __attribute__((ext_vector_type(8))) short bf16x8;
typedef __attribute__((ext_vector_type(4))) float f32x4;

__device__ __forceinline__ float bf2f(unsigned short u){
  union { unsigned int i; float f; } v; v.i = ((unsigned int)u) << 16; return v.f;
}
__device__ __forceinline__ unsigned short f2bf(float f){
  unsigned int u = __float_as_uint(f);
  unsigned int r = (u + 0x7FFFu + ((u >> 16) & 1u)) >> 16;
  return (unsigned short)r;
}
__device__ __forceinline__ float sigm(float x){ return 1.f / (1.f + __expf(-x)); }
__device__ __forceinline__ float ftanh(float x){ float e = __expf(2.f * x); return 1.f - 2.f / (e + 1.f); }

// ---- coherence helpers: L2-bypass (sc0 sc1) loads for cross-block data; RELAXED -> no cache inv ----
__device__ __forceinline__ float ldsys_f(const float* p2){
  return __hip_atomic_load((float*)p2, __ATOMIC_RELAXED, __HIP_MEMORY_SCOPE_SYSTEM);
}
__device__ __forceinline__ float2 ldsys_f2(const float* p2){
  unsigned long long u = __hip_atomic_load((unsigned long long*)p2, __ATOMIC_RELAXED, __HIP_MEMORY_SCOPE_SYSTEM);
  union { unsigned long long u; float2 f; } c; c.u = u; return c.f;
}
__device__ __forceinline__ bf16x8 ldsys_x8(const unsigned short* p2){
  unsigned long long a = __hip_atomic_load((unsigned long long*)p2, __ATOMIC_RELAXED, __HIP_MEMORY_SCOPE_SYSTEM);
  unsigned long long b = __hip_atomic_load((unsigned long long*)(p2 + 4), __ATOMIC_RELAXED, __HIP_MEMORY_SCOPE_SYSTEM);
  union { unsigned long long u[2]; bf16x8 v; } c; c.u[0] = a; c.u[1] = b; return c.v;
}

// ---- no-invalidate grid barrier: RELEASE arrive (buffer_wbl2, writeback-only) + RELAXED spin.
// L2 is never invalidated -> static data (encc/wqT/w_mel/xs16/ac/dc/weights) stays warm across steps.
// Safe because all cross-block READS use ldsys_* (L2-bypass) and all blocks are co-resident
// (cooperative launch). Counter region is memset to 0 every launch -> replay-deterministic.
__device__ __forceinline__ void gbar(unsigned* cnt, unsigned tgt){
  __builtin_amdgcn_s_waitcnt(0);     // each thread drains its own stores into L2
  __syncthreads();                   // all threads of block done + drained
  if (threadIdx.x == 0){
    __hip_atomic_fetch_add(cnt, 1u, __ATOMIC_RELEASE, __HIP_MEMORY_SCOPE_SYSTEM);  // wbl2 + add at LLC
    while (__hip_atomic_load(cnt, __ATOMIC_RELAXED, __HIP_MEMORY_SCOPE_SYSTEM) < tgt)
      __builtin_amdgcn_s_sleep(8);
  }
  __syncthreads();
}

// ---------------- workspace layout (float offsets); total 14,407,936 fl = 57.63 MB ----------------
#define OFF_ENCC    0           // 32*512*128
#define OFF_AH      2097152     // 2*32*1024
#define OFF_AC      2162688     // 32*1024
#define OFF_DH      2195456     // 2*32*1024
#define OFF_DC      2260992     // 32*1024
#define OFF_CTX2    2293760     // 2*32*512 (double-buffered ctx)
#define OFF_WQT     2342912     // 131072 fl (transposed/blocked w_q)
#define OFF_KA2     2473984     // 3968 fl
#define OFF_KB2     2477952     // 3968 fl
#define OFF_BAR     2887680     // 256 fl: [0] = barrier arrival counter (zeroed每 launch)
#define OFF_XBUF    2887936     // ushort region: x1hi/x1lo (57344 each), x2hi/x2lo (81920 each) -> 139264 fl
#define OFF_BIAS1   3029248     // 4096
#define OFF_BIAS2   3033344     // 4096
#define OFF_XS16    3037440     // ushort region: 600*32*256 = 4,915,200 ush -> 2,457,600 fl
#define OFF_WP      5495040     // ushort region: wp1 7,340,032 + wp2 10,485,760 ush -> 8,912,896 fl
#define TOTAL_FL    14407936
#define ZERO_BEG    2097152
#define ZERO_CNT    930048      // floats: AH .. XBUF end (covers OFF_BAR)

struct P {
  const float *enc, *mels, *w_pre1, *w_pre2;
  const float *w_ih1, *w_hh1, *b_ih1, *b_hh1;
  const float *w_q, *b_q, *w_enc, *k_loc, *w_loc, *w_e;
  const float *w_ih2, *w_hh2, *b_ih2, *b_hh2;
  const float *w_mel, *b_mel, *w_stop, *b_stop;
  float *encc;
  float *ah, *ac, *dh, *dc, *ctx2;
  float *wqT, *ka2, *kb2, *bias1, *bias2;
  unsigned short *xs16, *x1hi, *x1lo, *x2hi, *x2lo, *wp1, *wp2;
  float *out_mel, *out_stop, *out_attn;
  unsigned *bar;
};

__global__ void __launch_bounds__(256) k_sentinel(float* out, int n, float v){
  int i = blockIdx.x * 256 + threadIdx.x;
  if (i < n) out[i] = v;
}

// ---------------- setup: fused prenet (whole sequence, teacher-forced) ----------------
__global__ void __launch_bounds__(256) k_prenet(P p){
  __shared__ float in0[2000];   // 25 x 80
  __shared__ float h1[6400];    // 25 x 256
  const int b = blockIdx.x / 24, c = blockIdx.x % 24;
  const int j = threadIdx.x;
  for (int i = j; i < 2000; i += 256){
    const int tt = i / 80, k = i % 80;
    const int t = c * 25 + tt;
    in0[i] = (t == 0) ? 0.f : p.mels[(b * 600 + t - 1) * 80 + k];
  }
  __syncthreads();
  for (int tt = 0; tt < 25; ++tt){
    float acc = 0.f;
    const float* wr = p.w_pre1 + j * 80;
    const float* xr = in0 + tt * 80;
    for (int k = 0; k < 80; ++k) acc += xr[k] * wr[k];
    h1[tt * 256 + j] = fmaxf(acc, 0.f);
  }
  __syncthreads();
  for (int tt = 0; tt < 25; ++tt){
    float acc = 0.f;
    const float* wr = p.w_pre2 + j * 256;
    const float* xr = h1 + tt * 256;
    for (int k = 0; k < 256; k += 4){
      float4 x4 = *(const float4*)(xr + k); float4 w4 = *(const float4*)(wr + k);
      acc += x4.x * w4.x + x4.y * w4.y + x4.z * w4.z + x4.w * w4.w;
    }
    p.xs16[((c * 25 + tt) * 32 + b) * 256 + j] = f2bf(fmaxf(acc, 0.f));
  }
}

// ---------------- setup: enc_cache = enc @ w_enc^T  (fp32) ----------------
__global__ void __launch_bounds__(256) k_encc(P p){
  __shared__ float ex[8192];   // 16 x 512
  const int b = blockIdx.x >> 5, sc = blockIdx.x & 31;
  const int tid = threadIdx.x;
  for (int i = tid; i < 8192; i += 256){
    const int ss = i >> 9, k = i & 511;
    ex[i] = p.enc[((b * 512) + sc * 16 + ss) * 512 + k];
  }
  __syncthreads();
  const int a = tid & 127, sh = tid >> 7;
  const float* wr = p.w_enc + a * 512;
  for (int s8 = 0; s8 < 8; ++s8){
    const int ss = sh * 8 + s8;
    const float* xr = ex + ss * 512;
    float acc = 0.f;
    for (int k = 0; k < 512; k += 4){
      float4 x4 = *(const float4*)(xr + k); float4 w4 = *(const float4*)(wr + k);
      acc += x4.x * w4.x + x4.y * w4.y + x4.z * w4.z + x4.w * w4.w;
    }
    p.encc[((b * 512) + sc * 16 + ss) * 128 + a] = acc;
  }
}

// ---------------- setup: fused biases, KA2/KB2 = w_loc @ k_loc, blocked-transposed w_q ----------------
__global__ void __launch_bounds__(256) k_small(P p){
  const int i = blockIdx.x * 256 + threadIdx.x;
  if (i < 4096){
    p.bias1[i] = p.b_ih1[i] + p.b_hh1[i];
    p.bias2[i] = p.b_ih2[i] + p.b_hh2[i];
  }
  if (i < 3968){
    const int a = i / 31, dk = i % 31;
    float sa = 0.f, sb = 0.f;
    for (int f = 0; f < 32; ++f){
      const float wl = p.w_loc[a * 32 + f];
      sa += wl * p.k_loc[(f * 2 + 0) * 31 + dk];
      sb += wl * p.k_loc[(f * 2 + 1) * 31 + dk];
    }
    p.ka2[i] = sa; p.kb2[i] = sb;
  }
  if (i < 131072){
    // wqT[tid][k'] with tid=(kq*128+a): thread-contiguous 256-fl rows
    const int row = i >> 8, k2 = i & 255;
    const int a = row & 127, kq = row >> 7;
    p.wqT[i] = p.w_q[a * 1024 + kq * 256 + k2];
  }
}

// ---------------- setup: pack LSTM weights (fp32 -> bf16) into MFMA B-fragment order ----------------
__global__ void __launch_bounds__(256) k_packw(P p){
  const int stride = gridDim.x * 256;
  for (int i = blockIdx.x * 256 + threadIdx.x; i < 7340032; i += stride){
    const int j = i & 7, rest = i >> 3;
    const int lane = rest & 63, t2 = rest >> 6;
    const int kc = t2 % 56, nt = t2 / 56;
    const int np = nt * 16 + (lane & 15);
    const int k = kc * 32 + (lane >> 4) * 8 + j;
    const int row = (np & 3) * 1024 + (np >> 2);
    p.wp1[i] = f2bf((k < 768) ? p.w_ih1[row * 768 + k] : p.w_hh1[row * 1024 + (k - 768)]);
  }
  for (int i = blockIdx.x * 256 + threadIdx.x; i < 10485760; i += stride){
    const int j = i & 7, rest = i >> 3;
    const int lane = rest & 63, t2 = rest >> 6;
    const int kc = t2 % 80, nt = t2 / 80;
    const int np = nt * 16 + (lane & 15);
    const int k = kc * 32 + (lane >> 4) * 8 + j;
    const int row = (np & 3) * 1024 + (np >> 2);
    p.wp2[i] = f2bf((k < 1536) ? p.w_ih2[row * 1536 + k] : p.w_hh2[row * 1024 + (k - 1536)]);
  }
}

// ---------------- persistent decoder: 256 blocks x 512 threads, 2 custom barriers per step ----------------
// LDS: s_w 139264 + scratch 16384 + awp/cump 4352 + e 2048 + q 512 = 162,560 B <= 160 KiB
// Cross-block data (x1/x2, ah/dh, ctx2) is READ via ldsys_* (sc0 sc1, LLC) and published by the
// barrier's RELEASE-wbl2; everything static stays warm in per-XCD L2 (never invalidated).
__global__ void __attribute__((amdgpu_flat_work_group_size(512,512), amdgpu_waves_per_eu(2,2))) k_decoder(P p){
  const int blk = blockIdx.x;
  const int tid = threadIdx.x;

  __shared__ __align__(16) unsigned short s_w[69632];  // wp1 slice [0..28672) + wp2 slice [28672..69632)
  __shared__ __align__(16) float s_scratch[4096];
  __shared__ __align__(16) float s_awp[544];           // 16-zero pad each side of aw[512]
  __shared__ __align__(16) float s_cump[544];
  __shared__ float s_e[512];
  __shared__ float s_q[128];

  const int nt = blk;                 // N-tile for phase M (weights LDS-resident, order free)
  const int bb = blk & 31, xx = blk >> 5;

  // ---- one-time: weights -> LDS; aw/cum (incl. BOTH halo pads) zero ----
  {
    const uint4* s1 = (const uint4*)(p.wp1 + nt * 28672);
    uint4* d = (uint4*)s_w;
    for (int i = tid; i < 3584; i += 512) d[i] = s1[i];
    const uint4* s2 = (const uint4*)(p.wp2 + nt * 40960);
    for (int i = tid; i < 5120; i += 512) d[3584 + i] = s2[i];
    for (int i = tid; i < 544; i += 512){ s_awp[i] = 0.f; s_cump[i] = 0.f; }
  }
  const int aC = tid & 127, slC = tid >> 7;
  // ---- one-time: KA2/KB2 rows + w_e into registers ----
  float ka[31], kb[31];
  {
    const float* kap = p.ka2 + aC * 31;
    const float* kbp = p.kb2 + aC * 31;
    #pragma unroll
    for (int dk = 0; dk < 31; ++dk){ ka[dk] = kap[dk]; kb[dk] = kbp[dk]; }
  }
  const float wea = p.w_e[aC];
  // ---- one-time: enc ctx-slice -> 64 PERMANENT registers (asm pin defeats rematerialization) ----
  float er[64];
  {
    const int s4 = tid >> 6, dl = tid & 63;
    const float* ep = p.enc + ((bb * 512) + s4 * 64) * 512 + xx * 64 + dl;
    #pragma unroll
    for (int ss = 0; ss < 64; ++ss) er[ss] = ep[ss * 512];
    #pragma unroll
    for (int ss = 0; ss < 64; ++ss) asm volatile("" : "+v"(er[ss]));
  }
  __syncthreads();

  unsigned tgt = 0;
  for (int t = 0; t <= 600; ++t){
    const int pn = (t + 1) & 1;

    // ===== Phase M: LSTM1(t) [waves 0-3] and LSTM2(t-1) [waves 4-7], MFMA, weights from LDS =====
    {
      const bool is2 = (tid >= 256);
      const int tt = tid & 255;
      const int w = tt >> 6, lane = tt & 63;
      const int mt = w >> 1, kh = w & 1;
      const int col = lane & 15, q4 = lane >> 4;
      const bool active = is2 ? (t > 0) : (t < 600);
      f32x4 acc; acc.x = 0.f; acc.y = 0.f; acc.z = 0.f; acc.w = 0.f;
      if (active){
        const int m = mt * 16 + col;
        if (!is2){
          const unsigned short* wlp = s_w + lane * 8;
          const unsigned short* xh = p.x1hi + m * 1792 + q4 * 8;
          const unsigned short* xl = p.x1lo + m * 1792 + q4 * 8;
          int kc0 = kh * 28;
          if (kh == 0){
            const unsigned short* xs = p.xs16 + (t * 32 + m) * 256 + q4 * 8;   // static: normal loads
            #pragma unroll
            for (int kc = 0; kc < 8; ++kc){
              bf16x8 a0 = *(const bf16x8*)(xs + kc * 32);
              bf16x8 bw = *(const bf16x8*)(wlp + kc * 512);
              acc = __builtin_amdgcn_mfma_f32_16x16x32_bf16(a0, bw, acc, 0, 0, 0);
            }
            kc0 = 8;
          }
          const int kcEnd = kh * 28 + 28;
          for (int kc = kc0; kc < kcEnd; ++kc){
            bf16x8 a0 = ldsys_x8(xh + kc * 32);
            bf16x8 a1 = ldsys_x8(xl + kc * 32);
            bf16x8 bw = *(const bf16x8*)(wlp + kc * 512);
            acc = __builtin_amdgcn_mfma_f32_16x16x32_bf16(a0, bw, acc, 0, 0, 0);
            acc = __builtin_amdgcn_mfma_f32_16x16x32_bf16(a1, bw, acc, 0, 0, 0);
          }
        } else {
          const unsigned short* wlp = s_w + 28672 + lane * 8;
          const unsigned short* xh = p.x2hi + m * 2560 + q4 * 8;
          const unsigned short* xl = p.x2lo + m * 2560 + q4 * 8;
          const int kcBeg = kh * 40, kcEnd = kcBeg + 40;
          for (int kc = kcBeg; kc < kcEnd; ++kc){
            bf16x8 a0 = ldsys_x8(xh + kc * 32);
            bf16x8 a1 = ldsys_x8(xl + kc * 32);
            bf16x8 bw = *(const bf16x8*)(wlp + kc * 512);
            acc = __builtin_amdgcn_mfma_f32_16x16x32_bf16(a0, bw, acc, 0, 0, 0);
            acc = __builtin_amdgcn_mfma_f32_16x16x32_bf16(a1, bw, acc, 0, 0, 0);
          }
        }
      }
      float* red = s_scratch + (is2 ? 512 : 0);
      if (active && kh == 1){
        red[mt * 256 + lane * 4 + 0] = acc.x;
        red[mt * 256 + lane * 4 + 1] = acc.y;
        red[mt * 256 + lane * 4 + 2] = acc.z;
        red[mt * 256 + lane * 4 + 3] = acc.w;
      }
      __syncthreads();
      if (active && kh == 0){
        acc.x += red[mt * 256 + lane * 4 + 0];
        acc.y += red[mt * 256 + lane * 4 + 1];
        acc.z += red[mt * 256 + lane * 4 + 2];
        acc.w += red[mt * 256 + lane * 4 + 3];
        float vi[4], vf[4], vg[4], vo[4];
        #pragma unroll
        for (int r = 0; r < 4; ++r){
          float a = (r == 0) ? acc.x : (r == 1) ? acc.y : (r == 2) ? acc.z : acc.w;
          float b1 = __shfl_xor(a, 1);
          float b2 = __shfl_xor(a, 2);
          float b3 = __shfl_xor(b1, 2);
          vi[r] = a; vf[r] = b1; vg[r] = b2; vo[r] = b3;
        }
        if ((col & 3) == 0){
          const int u = nt * 4 + (col >> 2);
          const float* bias = is2 ? p.bias2 : p.bias1;
          const float bi = bias[u], bfv = bias[1024 + u], bg = bias[2048 + u], bo = bias[3072 + u];
          float* cbuf = is2 ? p.dc : p.ac;     // block-private: normal (stays warm in local L2)
          float* hbuf = (is2 ? p.dh : p.ah) + pn * 32768;
          #pragma unroll
          for (int r = 0; r < 4; ++r){
            const int br = mt * 16 + q4 * 4 + r;
            float c_ = sigm(vf[r] + bfv) * cbuf[br * 1024 + u] + sigm(vi[r] + bi) * ftanh(vg[r] + bg);
            cbuf[br * 1024 + u] = c_;
            hbuf[br * 1024 + u] = sigm(vo[r] + bo) * ftanh(c_);
          }
        }
      }
    }
    tgt += 256; gbar(p.bar, tgt);

    // ===== Phase ATTN (block-local; per block: bb row, xx d-chunk) =====

    // out-proj(t-1): spread across the 8 xx blocks (10 mel rows each); stop on xx==0
    if (t > 0 && tid < 22 && (tid < 20 || xx == 0)){
      const int pidx = tid >> 1, hf = tid & 1;
      const bool isMel = (pidx < 10);
      const int m2 = xx * 10 + pidx;
      const float* dhv = p.dh + pn * 32768 + bb * 1024;
      const float* ctxv = p.ctx2 + pn * 16384 + bb * 512;
      const float* wr = isMel ? (p.w_mel + m2 * 1536 + hf * 768) : (p.w_stop + hf * 768);
      float s = 0.f;
      if (hf == 0){
        for (int k = 0; k < 768; k += 4){
          float2 xa = ldsys_f2(dhv + k), xb2 = ldsys_f2(dhv + k + 2);
          float4 w4 = *(const float4*)(wr + k);
          s += xa.x * w4.x + xa.y * w4.y + xb2.x * w4.z + xb2.y * w4.w;
        }
      } else {
        for (int k = 0; k < 256; k += 4){
          float2 xa = ldsys_f2(dhv + 768 + k), xb2 = ldsys_f2(dhv + 768 + k + 2);
          float4 w4 = *(const float4*)(wr + k);
          s += xa.x * w4.x + xa.y * w4.y + xb2.x * w4.z + xb2.y * w4.w;
        }
        for (int k = 0; k < 512; k += 4){
          float2 xa = ldsys_f2(ctxv + k), xb2 = ldsys_f2(ctxv + k + 2);
          float4 w4 = *(const float4*)(wr + 256 + k);
          s += xa.x * w4.x + xa.y * w4.y + xb2.x * w4.z + xb2.y * w4.w;
        }
      }
      s += __shfl_xor(s, 1);
      if (hf == 0){
        if (isMel) p.out_mel[(bb * 600 + (t - 1)) * 80 + m2] = s + p.b_mel[m2];
        else       p.out_stop[bb * 600 + (t - 1)] = s + p.b_stop[0];
      }
    }

    if (t < 600){
      // repack ah(t)/dh(t-1) -> x1/x2 (this block's 384-slot share)
      if (tid < 384){
        const int kk = xx * 384 + tid;
        const float* ahv = p.ah + pn * 32768;
        const float* dhv = p.dh + pn * 32768;
        float v; unsigned short *hb, *lb; int slot;
        if (kk < 1024){ v = ldsys_f(ahv + bb * 1024 + kk); hb = p.x1hi; lb = p.x1lo; slot = bb * 1792 + 768 + kk; }
        else if (kk < 2048){ const int k2 = kk - 1024; v = ldsys_f(ahv + bb * 1024 + k2); hb = p.x2hi; lb = p.x2lo; slot = bb * 2560 + k2; }
        else { const int k2 = kk - 2048; v = ldsys_f(dhv + bb * 1024 + k2); hb = p.x2hi; lb = p.x2lo; slot = bb * 2560 + 1536 + k2; }
        const unsigned short h = f2bf(v);
        hb[slot] = h; lb[slot] = f2bf(v - bf2f(h));
      }
      // q(t) redundant per block: thread (aC, slC) quarter-dot, thread-contiguous wqT rows
      {
        const float* wv = p.wqT + tid * 256;        // static: normal (L2-warm)
        const float* av = p.ah + pn * 32768 + bb * 1024 + slC * 256;
        float s = 0.f;
        for (int k = 0; k < 256; k += 4){
          float2 xa = ldsys_f2(av + k), xb2 = ldsys_f2(av + k + 2);
          float4 w4 = *(const float4*)(wv + k);
          s += xa.x * w4.x + xa.y * w4.y + xb2.x * w4.z + xb2.y * w4.w;
        }
        s_scratch[tid] = s;
      }
      __syncthreads();
      if (tid < 128)
        s_q[tid] = s_scratch[tid] + s_scratch[128 + tid] + s_scratch[256 + tid] + s_scratch[384 + tid] + p.b_q[tid];
      __syncthreads();
      const float qa = s_q[aC];

      // e[s] for ALL 512 s (redundant across the 8 xx blocks): 16 chunks of 32 rows,
      // chunk order rotated by xx; encc loads double-buffered (prefetch cc+1 during cc).
      // encc is static -> normal loads, now L2-resident across steps.
      int ch = (xx * 2) & 15;
      float ec[8];
      {
        const float* eb = p.encc + (bb * 512 + ch * 32 + slC * 8) * 128 + aC;
        #pragma unroll
        for (int si = 0; si < 8; ++si) ec[si] = eb[si * 128];
      }
      for (int cc = 0; cc < 16; ++cc){
        const int chn = (cc + 1 + xx * 2) & 15;
        float ecn[8];
        if (cc < 15){
          const float* eb = p.encc + (bb * 512 + chn * 32 + slC * 8) * 128 + aC;
          #pragma unroll
          for (int si = 0; si < 8; ++si) ecn[si] = eb[si * 128];
        }
        float vv[8];
        {
          float va[40];
          const float* awb = s_awp + ch * 32 + slC * 8;    // 16B-aligned
          #pragma unroll
          for (int w4i = 0; w4i < 10; ++w4i){
            float4 t4 = *(const float4*)(awb + w4i * 4);
            va[w4i*4+0] = t4.x; va[w4i*4+1] = t4.y; va[w4i*4+2] = t4.z; va[w4i*4+3] = t4.w;
          }
          #pragma unroll
          for (int si = 0; si < 8; ++si){
            float v = qa + ec[si];
            #pragma unroll
            for (int dk = 0; dk < 31; ++dk) v += ka[dk] * va[si + dk + 1];
            vv[si] = v;
          }
        }
        {
          float vc[40];
          const float* cub = s_cump + ch * 32 + slC * 8;
          #pragma unroll
          for (int w4i = 0; w4i < 10; ++w4i){
            float4 u4 = *(const float4*)(cub + w4i * 4);
            vc[w4i*4+0] = u4.x; vc[w4i*4+1] = u4.y; vc[w4i*4+2] = u4.z; vc[w4i*4+3] = u4.w;
          }
          #pragma unroll
          for (int si = 0; si < 8; ++si){
            float v = vv[si];
            #pragma unroll
            for (int dk = 0; dk < 31; ++dk) v += kb[dk] * vc[si + dk + 1];
            s_scratch[(slC * 8 + si) * 128 + aC] = ftanh(v) * wea;
          }
        }
        __syncthreads();
        if (tid < 256){
          const int i2 = tid >> 3, p8 = tid & 7;
          float ssum = 0.f;
          const float* rr = s_scratch + i2 * 128 + p8 * 16;
          #pragma unroll
          for (int k = 0; k < 16; ++k) ssum += rr[k];
          ssum += __shfl_xor(ssum, 1); ssum += __shfl_xor(ssum, 2); ssum += __shfl_xor(ssum, 4);
          if (p8 == 0) s_e[ch * 32 + i2] = ssum;
        }
        __syncthreads();
        ch = chn;
        #pragma unroll
        for (int si = 0; si < 8; ++si) ec[si] = ecn[si];
      }

      // block-local softmax -> aw, cum
      {
        const int wid = tid >> 6, lane = tid & 63;
        const float v = s_e[tid];
        float mx = v;
        #pragma unroll
        for (int off = 32; off >= 1; off >>= 1) mx = fmaxf(mx, __shfl_xor(mx, off));
        if (lane == 0) s_scratch[wid] = mx;
        __syncthreads();
        mx = s_scratch[0];
        #pragma unroll
        for (int j = 1; j < 8; ++j) mx = fmaxf(mx, s_scratch[j]);
        const float wv2 = __expf(v - mx);
        float ps = wv2;
        #pragma unroll
        for (int off = 32; off >= 1; off >>= 1) ps += __shfl_xor(ps, off);
        if (lane == 0) s_scratch[8 + wid] = ps;
        __syncthreads();
        ps = 0.f;
        #pragma unroll
        for (int j = 0; j < 8; ++j) ps += s_scratch[8 + j];
        const float inv = 1.f / ps;
        const float awv = wv2 * inv;
        s_awp[16 + tid] = awv;
        s_cump[16 + tid] += awv;
        if (xx == (bb & 7)) p.out_attn[(bb * 600 + t) * 512 + tid] = awv;
      }
      __syncthreads();

      // ctx d-chunk (this block's 64 d values) from the permanently-pinned enc registers
      {
        const int s4 = tid >> 6;
        const float* awb2 = s_awp + 16 + s4 * 64;
        float accc = 0.f;
        #pragma unroll
        for (int ss4 = 0; ss4 < 16; ++ss4){
          const float4 a4 = *(const float4*)(awb2 + ss4 * 4);
          accc += a4.x * er[ss4 * 4 + 0] + a4.y * er[ss4 * 4 + 1]
                + a4.z * er[ss4 * 4 + 2] + a4.w * er[ss4 * 4 + 3];
        }
        s_scratch[tid] = accc;
        __syncthreads();
        if (tid < 64){
          float r0 = 0.f;
          #pragma unroll
          for (int j2 = 0; j2 < 8; ++j2) r0 += s_scratch[j2 * 64 + tid];
          const int d2 = xx * 64 + tid;
          p.ctx2[(1 - pn) * 16384 + bb * 512 + d2] = r0;
          const unsigned short h = f2bf(r0);
          const unsigned short l = f2bf(r0 - bf2f(h));
          p.x1hi[bb * 1792 + 256 + d2] = h;  p.x1lo[bb * 1792 + 256 + d2] = l;
          p.x2hi[bb * 2560 + 1024 + d2] = h; p.x2lo[bb * 2560 + 1024 + d2] = l;
        }
      }
    }

    if (t == 600) break;
    tgt += 256; gbar(p.bar, tgt);
  }
}

extern "C" void kernel_launch(void* const* d_in, const int* in_sizes, int n_in,
                              void* d_out, int out_size, void* d_ws, size_t ws_size,
                              hipStream_t stream){
  float* outp = (float*)d_out;

  if (ws_size < (size_t)TOTAL_FL * 4){
    hipLaunchKernelGGL(k_sentinel, dim3(16), dim3(256), 0, stream, outp, 4096, 1.0f);
    return;
  }

  P p;
  p.enc    = (const float*)d_in[0];
  p.mels   = (const float*)d_in[2];
  p.w_pre1 = (const float*)d_in[3];
  p.w_pre2 = (const float*)d_in[4];
  p.w_ih1  = (const float*)d_in[5];
  p.w_hh1  = (const float*)d_in[6];
  p.b_ih1  = (const float*)d_in[7];
  p.b_hh1  = (const float*)d_in[8];
  p.w_q    = (const float*)d_in[9];
  p.b_q    = (const float*)d_in[10];
  p.w_enc  = (const float*)d_in[11];
  p.k_loc  = (const float*)d_in[12];
  p.w_loc  = (const float*)d_in[13];
  p.w_e    = (const float*)d_in[14];
  p.w_ih2  = (const float*)d_in[15];
  p.w_hh2  = (const float*)d_in[16];
  p.b_ih2  = (const float*)d_in[17];
  p.b_hh2  = (const float*)d_in[18];
  p.w_mel  = (const float*)d_in[19];
  p.b_mel  = (const float*)d_in[20];
  p.w_stop = (const float*)d_in[21];
  p.b_stop = (const float*)d_in[22];

  float* ws = (float*)d_ws;
  p.encc = ws + OFF_ENCC;
  p.ah   = ws + OFF_AH;    p.ac   = ws + OFF_AC;
  p.dh   = ws + OFF_DH;    p.dc   = ws + OFF_DC;
  p.ctx2 = ws + OFF_CTX2;
  p.wqT  = ws + OFF_WQT;
  p.ka2  = ws + OFF_KA2;   p.kb2  = ws + OFF_KB2;
  p.bias1 = ws + OFF_BIAS1; p.bias2 = ws + OFF_BIAS2;
  p.bar   = (unsigned*)(ws + OFF_BAR);
  unsigned short* xb = (unsigned short*)(ws + OFF_XBUF);
  p.x1hi = xb;             p.x1lo = xb + 57344;
  p.x2hi = xb + 114688;    p.x2lo = xb + 196608;
  p.xs16 = (unsigned short*)(ws + OFF_XS16);
  unsigned short* wpb = (unsigned short*)(ws + OFF_WP);
  p.wp1  = wpb;            p.wp2  = wpb + 7340032;

  p.out_mel  = outp;
  p.out_stop = outp + 1536000;
  p.out_attn = outp + 1555200;

  hipMemsetAsync((void*)(ws + ZERO_BEG), 0, (size_t)ZERO_CNT * 4, stream);
  hipLaunchKernelGGL(k_prenet, dim3(768), dim3(256), 0, stream, p);
  hipLaunchKernelGGL(k_encc,   dim3(1024), dim3(256), 0, stream, p);
  hipLaunchKernelGGL(k_small,  dim3(512), dim3(256), 0, stream, p);
  hipLaunchKernelGGL(k_packw,  dim3(2048), dim3(256), 0, stream, p);

  void* args[] = { &p };
  hipError_t err = hipLaunchCooperativeKernel((void*)k_decoder, dim3(256), dim3(512), args, 0, stream);
  if (err != hipSuccess){
    hipLaunchKernelGGL(k_sentinel, dim3(16), dim3(256), 0, stream, outp, 4096, 4.0f);
  }
}

// Round 7
// 107936.047 us; speedup vs baseline: 1.0517x; 1.0517x over previous
//
#include <hip/hip_runtime.h>
#include <hip/hip_cooperative_groups.h>

namespace cg = cooperative_groups;

typedef __attribute__((ext_vector_type(8))) short bf16x8;
typedef __attribute__((ext_vector_type(4))) float f32x4;

__device__ __forceinline__ float bf2f(unsigned short u){
  union { unsigned int i; float f; } v; v.i = ((unsigned int)u) << 16; return v.f;
}
__device__ __forceinline__ unsigned short f2bf(float f){
  unsigned int u = __float_as_uint(f);
  unsigned int r = (u + 0x7FFFu + ((u >> 16) & 1u)) >> 16;
  return (unsigned short)r;
}
__device__ __forceinline__ float sigm(float x){ return 1.f / (1.f + __expf(-x)); }
__device__ __forceinline__ float ftanh(float x){ float e = __expf(2.f * x); return 1.f - 2.f / (e + 1.f); }

// ---- coherence helpers: L2-bypass (sc0 sc1) accesses for cross-block data ----
// Reads hit the LLC coherence point; writes go straight to LLC (no local-L2 dirty state).
__device__ __forceinline__ float ldsys_f(const float* p2){
  return __hip_atomic_load((float*)p2, __ATOMIC_RELAXED, __HIP_MEMORY_SCOPE_SYSTEM);
}
__device__ __forceinline__ float2 ldsys_f2(const float* p2){
  unsigned long long u = __hip_atomic_load((unsigned long long*)p2, __ATOMIC_RELAXED, __HIP_MEMORY_SCOPE_SYSTEM);
  union { unsigned long long u; float2 f; } c; c.u = u; return c.f;
}
__device__ __forceinline__ bf16x8 ldsys_x8(const unsigned short* p2){
  unsigned long long a = __hip_atomic_load((unsigned long long*)p2, __ATOMIC_RELAXED, __HIP_MEMORY_SCOPE_SYSTEM);
  unsigned long long b = __hip_atomic_load((unsigned long long*)(p2 + 4), __ATOMIC_RELAXED, __HIP_MEMORY_SCOPE_SYSTEM);
  union { unsigned long long u[2]; bf16x8 v; } c; c.u[0] = a; c.u[1] = b; return c.v;
}
__device__ __forceinline__ void stsys_f(float* p2, float v){
  __hip_atomic_store(p2, v, __ATOMIC_RELAXED, __HIP_MEMORY_SCOPE_SYSTEM);
}
__device__ __forceinline__ void stsys_u16(unsigned short* p2, unsigned short v){
  __hip_atomic_store(p2, v, __ATOMIC_RELAXED, __HIP_MEMORY_SCOPE_SYSTEM);
}

// ---- fence-free grid barrier: NO release (no buffer_wbl2 L2-walk), NO acquire (no buffer_inv).
// Publication protocol: every cross-block STORE is an sc0sc1 store (already at LLC);
// s_waitcnt(0) drains them to the LLC ack point before the block arrives; readers use
// ldsys_* bypass loads. L2 is never walked nor invalidated -> static data stays warm AND
// the per-barrier fixed cost collapses to one LLC atomic round + spin.
__device__ __forceinline__ void gbar(unsigned* cnt, unsigned tgt){
  __builtin_amdgcn_s_waitcnt(0);     // this thread's sc-stores have reached the LLC
  __syncthreads();                   // whole block done + drained
  if (threadIdx.x == 0){
    __hip_atomic_fetch_add(cnt, 1u, __ATOMIC_RELAXED, __HIP_MEMORY_SCOPE_SYSTEM);
    while (__hip_atomic_load(cnt, __ATOMIC_RELAXED, __HIP_MEMORY_SCOPE_SYSTEM) < tgt)
      __builtin_amdgcn_s_sleep(2);
  }
  __syncthreads();
}

// ---------------- workspace layout (float offsets); total 14,407,936 fl = 57.63 MB ----------------
#define OFF_ENCC    0           // 32*512*128
#define OFF_AH      2097152     // 2*32*1024
#define OFF_AC      2162688     // 32*1024
#define OFF_DH      2195456     // 2*32*1024
#define OFF_DC      2260992     // 32*1024
#define OFF_CTX2    2293760     // 2*32*512 (double-buffered ctx)
#define OFF_WQT     2342912     // 131072 fl (transposed/blocked w_q)
#define OFF_KA2     2473984     // 3968 fl
#define OFF_KB2     2477952     // 3968 fl
#define OFF_BAR     2887680     // 256 fl: [0] = barrier arrival counter (zeroed every launch)
#define OFF_XBUF    2887936     // ushort region: x1hi/x1lo (57344 each), x2hi/x2lo (81920 each) -> 139264 fl
#define OFF_BIAS1   3029248     // 4096
#define OFF_BIAS2   3033344     // 4096
#define OFF_XS16    3037440     // ushort region: 600*32*256 = 4,915,200 ush -> 2,457,600 fl
#define OFF_WP      5495040     // ushort region: wp1 7,340,032 + wp2 10,485,760 ush -> 8,912,896 fl
#define TOTAL_FL    14407936
#define ZERO_BEG    2097152
#define ZERO_CNT    930048      // floats: AH .. XBUF end (covers OFF_BAR)

struct P {
  const float *enc, *mels, *w_pre1, *w_pre2;
  const float *w_ih1, *w_hh1, *b_ih1, *b_hh1;
  const float *w_q, *b_q, *w_enc, *k_loc, *w_loc, *w_e;
  const float *w_ih2, *w_hh2, *b_ih2, *b_hh2;
  const float *w_mel, *b_mel, *w_stop, *b_stop;
  float *encc;
  float *ah, *ac, *dh, *dc, *ctx2;
  float *wqT, *ka2, *kb2, *bias1, *bias2;
  unsigned short *xs16, *x1hi, *x1lo, *x2hi, *x2lo, *wp1, *wp2;
  float *out_mel, *out_stop, *out_attn;
  unsigned *bar;
};

__global__ void __launch_bounds__(256) k_sentinel(float* out, int n, float v){
  int i = blockIdx.x * 256 + threadIdx.x;
  if (i < n) out[i] = v;
}

// ---------------- setup: fused prenet (whole sequence, teacher-forced) ----------------
__global__ void __launch_bounds__(256) k_prenet(P p){
  __shared__ float in0[2000];   // 25 x 80
  __shared__ float h1[6400];    // 25 x 256
  const int b = blockIdx.x / 24, c = blockIdx.x % 24;
  const int j = threadIdx.x;
  for (int i = j; i < 2000; i += 256){
    const int tt = i / 80, k = i % 80;
    const int t = c * 25 + tt;
    in0[i] = (t == 0) ? 0.f : p.mels[(b * 600 + t - 1) * 80 + k];
  }
  __syncthreads();
  for (int tt = 0; tt < 25; ++tt){
    float acc = 0.f;
    const float* wr = p.w_pre1 + j * 80;
    const float* xr = in0 + tt * 80;
    for (int k = 0; k < 80; ++k) acc += xr[k] * wr[k];
    h1[tt * 256 + j] = fmaxf(acc, 0.f);
  }
  __syncthreads();
  for (int tt = 0; tt < 25; ++tt){
    float acc = 0.f;
    const float* wr = p.w_pre2 + j * 256;
    const float* xr = h1 + tt * 256;
    for (int k = 0; k < 256; k += 4){
      float4 x4 = *(const float4*)(xr + k); float4 w4 = *(const float4*)(wr + k);
      acc += x4.x * w4.x + x4.y * w4.y + x4.z * w4.z + x4.w * w4.w;
    }
    p.xs16[((c * 25 + tt) * 32 + b) * 256 + j] = f2bf(fmaxf(acc, 0.f));
  }
}

// ---------------- setup: enc_cache = enc @ w_enc^T  (fp32) ----------------
__global__ void __launch_bounds__(256) k_encc(P p){
  __shared__ float ex[8192];   // 16 x 512
  const int b = blockIdx.x >> 5, sc = blockIdx.x & 31;
  const int tid = threadIdx.x;
  for (int i = tid; i < 8192; i += 256){
    const int ss = i >> 9, k = i & 511;
    ex[i] = p.enc[((b * 512) + sc * 16 + ss) * 512 + k];
  }
  __syncthreads();
  const int a = tid & 127, sh = tid >> 7;
  const float* wr = p.w_enc + a * 512;
  for (int s8 = 0; s8 < 8; ++s8){
    const int ss = sh * 8 + s8;
    const float* xr = ex + ss * 512;
    float acc = 0.f;
    for (int k = 0; k < 512; k += 4){
      float4 x4 = *(const float4*)(xr + k); float4 w4 = *(const float4*)(wr + k);
      acc += x4.x * w4.x + x4.y * w4.y + x4.z * w4.z + x4.w * w4.w;
    }
    p.encc[((b * 512) + sc * 16 + ss) * 128 + a] = acc;
  }
}

// ---------------- setup: fused biases, KA2/KB2 = w_loc @ k_loc, blocked-transposed w_q ----------------
__global__ void __launch_bounds__(256) k_small(P p){
  const int i = blockIdx.x * 256 + threadIdx.x;
  if (i < 4096){
    p.bias1[i] = p.b_ih1[i] + p.b_hh1[i];
    p.bias2[i] = p.b_ih2[i] + p.b_hh2[i];
  }
  if (i < 3968){
    const int a = i / 31, dk = i % 31;
    float sa = 0.f, sb = 0.f;
    for (int f = 0; f < 32; ++f){
      const float wl = p.w_loc[a * 32 + f];
      sa += wl * p.k_loc[(f * 2 + 0) * 31 + dk];
      sb += wl * p.k_loc[(f * 2 + 1) * 31 + dk];
    }
    p.ka2[i] = sa; p.kb2[i] = sb;
  }
  if (i < 131072){
    // wqT[tid][k'] with tid=(kq*128+a): thread-contiguous 256-fl rows
    const int row = i >> 8, k2 = i & 255;
    const int a = row & 127, kq = row >> 7;
    p.wqT[i] = p.w_q[a * 1024 + kq * 256 + k2];
  }
}

// ---------------- setup: pack LSTM weights (fp32 -> bf16) into MFMA B-fragment order ----------------
__global__ void __launch_bounds__(256) k_packw(P p){
  const int stride = gridDim.x * 256;
  for (int i = blockIdx.x * 256 + threadIdx.x; i < 7340032; i += stride){
    const int j = i & 7, rest = i >> 3;
    const int lane = rest & 63, t2 = rest >> 6;
    const int kc = t2 % 56, nt = t2 / 56;
    const int np = nt * 16 + (lane & 15);
    const int k = kc * 32 + (lane >> 4) * 8 + j;
    const int row = (np & 3) * 1024 + (np >> 2);
    p.wp1[i] = f2bf((k < 768) ? p.w_ih1[row * 768 + k] : p.w_hh1[row * 1024 + (k - 768)]);
  }
  for (int i = blockIdx.x * 256 + threadIdx.x; i < 10485760; i += stride){
    const int j = i & 7, rest = i >> 3;
    const int lane = rest & 63, t2 = rest >> 6;
    const int kc = t2 % 80, nt = t2 / 80;
    const int np = nt * 16 + (lane & 15);
    const int k = kc * 32 + (lane >> 4) * 8 + j;
    const int row = (np & 3) * 1024 + (np >> 2);
    p.wp2[i] = f2bf((k < 1536) ? p.w_ih2[row * 1536 + k] : p.w_hh2[row * 1024 + (k - 1536)]);
  }
}

// ---------------- persistent decoder: 256 blocks x 512 threads, 2 fence-free barriers per step ----------------
// LDS: s_w 139264 + scratch 16384 + awp/cump 4352 + e 2048 + q 512 = 162,560 B <= 160 KiB
// Cross-block data: sc0sc1 stores (straight to LLC) + sc0sc1 loads (bypass); NO wbl2 / NO inv ever.
__global__ void __attribute__((amdgpu_flat_work_group_size(512,512), amdgpu_waves_per_eu(2,2))) k_decoder(P p){
  const int blk = blockIdx.x;
  const int tid = threadIdx.x;

  __shared__ __align__(16) unsigned short s_w[69632];  // wp1 slice [0..28672) + wp2 slice [28672..69632)
  __shared__ __align__(16) float s_scratch[4096];
  __shared__ __align__(16) float s_awp[544];           // 16-zero pad each side of aw[512]
  __shared__ __align__(16) float s_cump[544];
  __shared__ float s_e[512];
  __shared__ float s_q[128];

  const int nt = blk;                 // N-tile for phase M (weights LDS-resident, order free)
  const int bb = blk & 31, xx = blk >> 5;

  // ---- one-time: weights -> LDS; aw/cum (incl. BOTH halo pads) zero ----
  {
    const uint4* s1 = (const uint4*)(p.wp1 + nt * 28672);
    uint4* d = (uint4*)s_w;
    for (int i = tid; i < 3584; i += 512) d[i] = s1[i];
    const uint4* s2 = (const uint4*)(p.wp2 + nt * 40960);
    for (int i = tid; i < 5120; i += 512) d[3584 + i] = s2[i];
    for (int i = tid; i < 544; i += 512){ s_awp[i] = 0.f; s_cump[i] = 0.f; }
  }
  const int aC = tid & 127, slC = tid >> 7;
  // ---- one-time: KA2/KB2 rows + w_e into registers ----
  float ka[31], kb[31];
  {
    const float* kap = p.ka2 + aC * 31;
    const float* kbp = p.kb2 + aC * 31;
    #pragma unroll
    for (int dk = 0; dk < 31; ++dk){ ka[dk] = kap[dk]; kb[dk] = kbp[dk]; }
  }
  const float wea = p.w_e[aC];
  // ---- one-time: enc ctx-slice -> 64 PERMANENT registers (asm pin defeats rematerialization) ----
  float er[64];
  {
    const int s4 = tid >> 6, dl = tid & 63;
    const float* ep = p.enc + ((bb * 512) + s4 * 64) * 512 + xx * 64 + dl;
    #pragma unroll
    for (int ss = 0; ss < 64; ++ss) er[ss] = ep[ss * 512];
    #pragma unroll
    for (int ss = 0; ss < 64; ++ss) asm volatile("" : "+v"(er[ss]));
  }
  __syncthreads();

  unsigned tgt = 0;
  for (int t = 0; t <= 600; ++t){
    const int pn = (t + 1) & 1;

    // ===== Phase M: LSTM1(t) [waves 0-3] and LSTM2(t-1) [waves 4-7], MFMA, weights from LDS =====
    {
      const bool is2 = (tid >= 256);
      const int tt = tid & 255;
      const int w = tt >> 6, lane = tt & 63;
      const int mt = w >> 1, kh = w & 1;
      const int col = lane & 15, q4 = lane >> 4;
      const bool active = is2 ? (t > 0) : (t < 600);
      f32x4 acc; acc.x = 0.f; acc.y = 0.f; acc.z = 0.f; acc.w = 0.f;
      if (active){
        const int m = mt * 16 + col;
        if (!is2){
          const unsigned short* wlp = s_w + lane * 8;
          const unsigned short* xh = p.x1hi + m * 1792 + q4 * 8;
          const unsigned short* xl = p.x1lo + m * 1792 + q4 * 8;
          int kc0 = kh * 28;
          if (kh == 0){
            const unsigned short* xs = p.xs16 + (t * 32 + m) * 256 + q4 * 8;   // static: normal loads
            #pragma unroll
            for (int kc = 0; kc < 8; ++kc){
              bf16x8 a0 = *(const bf16x8*)(xs + kc * 32);
              bf16x8 bw = *(const bf16x8*)(wlp + kc * 512);
              acc = __builtin_amdgcn_mfma_f32_16x16x32_bf16(a0, bw, acc, 0, 0, 0);
            }
            kc0 = 8;
          }
          const int kcEnd = kh * 28 + 28;
          for (int kc = kc0; kc < kcEnd; ++kc){
            bf16x8 a0 = ldsys_x8(xh + kc * 32);
            bf16x8 a1 = ldsys_x8(xl + kc * 32);
            bf16x8 bw = *(const bf16x8*)(wlp + kc * 512);
            acc = __builtin_amdgcn_mfma_f32_16x16x32_bf16(a0, bw, acc, 0, 0, 0);
            acc = __builtin_amdgcn_mfma_f32_16x16x32_bf16(a1, bw, acc, 0, 0, 0);
          }
        } else {
          const unsigned short* wlp = s_w + 28672 + lane * 8;
          const unsigned short* xh = p.x2hi + m * 2560 + q4 * 8;
          const unsigned short* xl = p.x2lo + m * 2560 + q4 * 8;
          const int kcBeg = kh * 40, kcEnd = kcBeg + 40;
          for (int kc = kcBeg; kc < kcEnd; ++kc){
            bf16x8 a0 = ldsys_x8(xh + kc * 32);
            bf16x8 a1 = ldsys_x8(xl + kc * 32);
            bf16x8 bw = *(const bf16x8*)(wlp + kc * 512);
            acc = __builtin_amdgcn_mfma_f32_16x16x32_bf16(a0, bw, acc, 0, 0, 0);
            acc = __builtin_amdgcn_mfma_f32_16x16x32_bf16(a1, bw, acc, 0, 0, 0);
          }
        }
      }
      float* red = s_scratch + (is2 ? 512 : 0);
      if (active && kh == 1){
        red[mt * 256 + lane * 4 + 0] = acc.x;
        red[mt * 256 + lane * 4 + 1] = acc.y;
        red[mt * 256 + lane * 4 + 2] = acc.z;
        red[mt * 256 + lane * 4 + 3] = acc.w;
      }
      __syncthreads();
      if (active && kh == 0){
        acc.x += red[mt * 256 + lane * 4 + 0];
        acc.y += red[mt * 256 + lane * 4 + 1];
        acc.z += red[mt * 256 + lane * 4 + 2];
        acc.w += red[mt * 256 + lane * 4 + 3];
        float vi[4], vf[4], vg[4], vo[4];
        #pragma unroll
        for (int r = 0; r < 4; ++r){
          float a = (r == 0) ? acc.x : (r == 1) ? acc.y : (r == 2) ? acc.z : acc.w;
          float b1 = __shfl_xor(a, 1);
          float b2 = __shfl_xor(a, 2);
          float b3 = __shfl_xor(b1, 2);
          vi[r] = a; vf[r] = b1; vg[r] = b2; vo[r] = b3;
        }
        if ((col & 3) == 0){
          const int u = nt * 4 + (col >> 2);
          const float* bias = is2 ? p.bias2 : p.bias1;
          const float bi = bias[u], bfv = bias[1024 + u], bg = bias[2048 + u], bo = bias[3072 + u];
          float* cbuf = is2 ? p.dc : p.ac;     // block-private: normal load/store, L2-warm
          float* hbuf = (is2 ? p.dh : p.ah) + pn * 32768;   // cross-block: sc-stores to LLC
          #pragma unroll
          for (int r = 0; r < 4; ++r){
            const int br = mt * 16 + q4 * 4 + r;
            float c_ = sigm(vf[r] + bfv) * cbuf[br * 1024 + u] + sigm(vi[r] + bi) * ftanh(vg[r] + bg);
            cbuf[br * 1024 + u] = c_;
            stsys_f(hbuf + br * 1024 + u, sigm(vo[r] + bo) * ftanh(c_));
          }
        }
      }
    }
    tgt += 256; gbar(p.bar, tgt);

    // ===== Phase ATTN (block-local; per block: bb row, xx d-chunk) =====

    // out-proj(t-1): spread across the 8 xx blocks (10 mel rows each); stop on xx==0
    if (t > 0 && tid < 22 && (tid < 20 || xx == 0)){
      const int pidx = tid >> 1, hf = tid & 1;
      const bool isMel = (pidx < 10);
      const int m2 = xx * 10 + pidx;
      const float* dhv = p.dh + pn * 32768 + bb * 1024;
      const float* ctxv = p.ctx2 + pn * 16384 + bb * 512;
      const float* wr = isMel ? (p.w_mel + m2 * 1536 + hf * 768) : (p.w_stop + hf * 768);
      float s = 0.f;
      if (hf == 0){
        for (int k = 0; k < 768; k += 4){
          float2 xa = ldsys_f2(dhv + k), xb2 = ldsys_f2(dhv + k + 2);
          float4 w4 = *(const float4*)(wr + k);
          s += xa.x * w4.x + xa.y * w4.y + xb2.x * w4.z + xb2.y * w4.w;
        }
      } else {
        for (int k = 0; k < 256; k += 4){
          float2 xa = ldsys_f2(dhv + 768 + k), xb2 = ldsys_f2(dhv + 768 + k + 2);
          float4 w4 = *(const float4*)(wr + k);
          s += xa.x * w4.x + xa.y * w4.y + xb2.x * w4.z + xb2.y * w4.w;
        }
        for (int k = 0; k < 512; k += 4){
          float2 xa = ldsys_f2(ctxv + k), xb2 = ldsys_f2(ctxv + k + 2);
          float4 w4 = *(const float4*)(wr + 256 + k);
          s += xa.x * w4.x + xa.y * w4.y + xb2.x * w4.z + xb2.y * w4.w;
        }
      }
      s += __shfl_xor(s, 1);
      if (hf == 0){
        if (isMel) p.out_mel[(bb * 600 + (t - 1)) * 80 + m2] = s + p.b_mel[m2];
        else       p.out_stop[bb * 600 + (t - 1)] = s + p.b_stop[0];
      }
    }

    if (t < 600){
      // repack ah(t)/dh(t-1) -> x1/x2 (this block's 384-slot share), sc-stores
      if (tid < 384){
        const int kk = xx * 384 + tid;
        const float* ahv = p.ah + pn * 32768;
        const float* dhv = p.dh + pn * 32768;
        float v; unsigned short *hb, *lb; int slot;
        if (kk < 1024){ v = ldsys_f(ahv + bb * 1024 + kk); hb = p.x1hi; lb = p.x1lo; slot = bb * 1792 + 768 + kk; }
        else if (kk < 2048){ const int k2 = kk - 1024; v = ldsys_f(ahv + bb * 1024 + k2); hb = p.x2hi; lb = p.x2lo; slot = bb * 2560 + k2; }
        else { const int k2 = kk - 2048; v = ldsys_f(dhv + bb * 1024 + k2); hb = p.x2hi; lb = p.x2lo; slot = bb * 2560 + 1536 + k2; }
        const unsigned short h = f2bf(v);
        stsys_u16(hb + slot, h); stsys_u16(lb + slot, f2bf(v - bf2f(h)));
      }
      // q(t) redundant per block: thread (aC, slC) quarter-dot, thread-contiguous wqT rows
      {
        const float* wv = p.wqT + tid * 256;        // static: normal (L2-warm)
        const float* av = p.ah + pn * 32768 + bb * 1024 + slC * 256;
        float s = 0.f;
        for (int k = 0; k < 256; k += 4){
          float2 xa = ldsys_f2(av + k), xb2 = ldsys_f2(av + k + 2);
          float4 w4 = *(const float4*)(wv + k);
          s += xa.x * w4.x + xa.y * w4.y + xb2.x * w4.z + xb2.y * w4.w;
        }
        s_scratch[tid] = s;
      }
      __syncthreads();
      if (tid < 128)
        s_q[tid] = s_scratch[tid] + s_scratch[128 + tid] + s_scratch[256 + tid] + s_scratch[384 + tid] + p.b_q[tid];
      __syncthreads();
      const float qa = s_q[aC];

      // e[s] for ALL 512 s (redundant across the 8 xx blocks): 16 chunks of 32 rows,
      // chunk order rotated by xx; encc loads double-buffered (prefetch cc+1 during cc).
      // encc is static -> normal loads, L2-resident across steps (never invalidated).
      int ch = (xx * 2) & 15;
      float ec[8];
      {
        const float* eb = p.encc + (bb * 512 + ch * 32 + slC * 8) * 128 + aC;
        #pragma unroll
        for (int si = 0; si < 8; ++si) ec[si] = eb[si * 128];
      }
      for (int cc = 0; cc < 16; ++cc){
        const int chn = (cc + 1 + xx * 2) & 15;
        float ecn[8];
        if (cc < 15){
          const float* eb = p.encc + (bb * 512 + chn * 32 + slC * 8) * 128 + aC;
          #pragma unroll
          for (int si = 0; si < 8; ++si) ecn[si] = eb[si * 128];
        }
        float vv[8];
        {
          float va[40];
          const float* awb = s_awp + ch * 32 + slC * 8;    // 16B-aligned
          #pragma unroll
          for (int w4i = 0; w4i < 10; ++w4i){
            float4 t4 = *(const float4*)(awb + w4i * 4);
            va[w4i*4+0] = t4.x; va[w4i*4+1] = t4.y; va[w4i*4+2] = t4.z; va[w4i*4+3] = t4.w;
          }
          #pragma unroll
          for (int si = 0; si < 8; ++si){
            float v = qa + ec[si];
            #pragma unroll
            for (int dk = 0; dk < 31; ++dk) v += ka[dk] * va[si + dk + 1];
            vv[si] = v;
          }
        }
        {
          float vc[40];
          const float* cub = s_cump + ch * 32 + slC * 8;
          #pragma unroll
          for (int w4i = 0; w4i < 10; ++w4i){
            float4 u4 = *(const float4*)(cub + w4i * 4);
            vc[w4i*4+0] = u4.x; vc[w4i*4+1] = u4.y; vc[w4i*4+2] = u4.z; vc[w4i*4+3] = u4.w;
          }
          #pragma unroll
          for (int si = 0; si < 8; ++si){
            float v = vv[si];
            #pragma unroll
            for (int dk = 0; dk < 31; ++dk) v += kb[dk] * vc[si + dk + 1];
            s_scratch[(slC * 8 + si) * 128 + aC] = ftanh(v) * wea;
          }
        }
        __syncthreads();
        if (tid < 256){
          const int i2 = tid >> 3, p8 = tid & 7;
          float ssum = 0.f;
          const float* rr = s_scratch + i2 * 128 + p8 * 16;
          #pragma unroll
          for (int k = 0; k < 16; ++k) ssum += rr[k];
          ssum += __shfl_xor(ssum, 1); ssum += __shfl_xor(ssum, 2); ssum += __shfl_xor(ssum, 4);
          if (p8 == 0) s_e[ch * 32 + i2] = ssum;
        }
        __syncthreads();
        ch = chn;
        #pragma unroll
        for (int si = 0; si < 8; ++si) ec[si] = ecn[si];
      }

      // block-local softmax -> aw, cum
      {
        const int wid = tid >> 6, lane = tid & 63;
        const float v = s_e[tid];
        float mx = v;
        #pragma unroll
        for (int off = 32; off >= 1; off >>= 1) mx = fmaxf(mx, __shfl_xor(mx, off));
        if (lane == 0) s_scratch[wid] = mx;
        __syncthreads();
        mx = s_scratch[0];
        #pragma unroll
        for (int j = 1; j < 8; ++j) mx = fmaxf(mx, s_scratch[j]);
        const float wv2 = __expf(v - mx);
        float ps = wv2;
        #pragma unroll
        for (int off = 32; off >= 1; off >>= 1) ps += __shfl_xor(ps, off);
        if (lane == 0) s_scratch[8 + wid] = ps;
        __syncthreads();
        ps = 0.f;
        #pragma unroll
        for (int j = 0; j < 8; ++j) ps += s_scratch[8 + j];
        const float inv = 1.f / ps;
        const float awv = wv2 * inv;
        s_awp[16 + tid] = awv;
        s_cump[16 + tid] += awv;
        if (xx == (bb & 7)) p.out_attn[(bb * 600 + t) * 512 + tid] = awv;
      }
      __syncthreads();

      // ctx d-chunk (this block's 64 d values) from the permanently-pinned enc registers
      {
        const int s4 = tid >> 6;
        const float* awb2 = s_awp + 16 + s4 * 64;
        float accc = 0.f;
        #pragma unroll
        for (int ss4 = 0; ss4 < 16; ++ss4){
          const float4 a4 = *(const float4*)(awb2 + ss4 * 4);
          accc += a4.x * er[ss4 * 4 + 0] + a4.y * er[ss4 * 4 + 1]
                + a4.z * er[ss4 * 4 + 2] + a4.w * er[ss4 * 4 + 3];
        }
        s_scratch[tid] = accc;
        __syncthreads();
        if (tid < 64){
          float r0 = 0.f;
          #pragma unroll
          for (int j2 = 0; j2 < 8; ++j2) r0 += s_scratch[j2 * 64 + tid];
          const int d2 = xx * 64 + tid;
          stsys_f(p.ctx2 + (1 - pn) * 16384 + bb * 512 + d2, r0);
          const unsigned short h = f2bf(r0);
          const unsigned short l = f2bf(r0 - bf2f(h));
          stsys_u16(p.x1hi + bb * 1792 + 256 + d2, h);  stsys_u16(p.x1lo + bb * 1792 + 256 + d2, l);
          stsys_u16(p.x2hi + bb * 2560 + 1024 + d2, h); stsys_u16(p.x2lo + bb * 2560 + 1024 + d2, l);
        }
      }
    }

    if (t == 600) break;
    tgt += 256; gbar(p.bar, tgt);
  }
}

extern "C" void kernel_launch(void* const* d_in, const int* in_sizes, int n_in,
                              void* d_out, int out_size, void* d_ws, size_t ws_size,
                              hipStream_t stream){
  float* outp = (float*)d_out;

  if (ws_size < (size_t)TOTAL_FL * 4){
    hipLaunchKernelGGL(k_sentinel, dim3(16), dim3(256), 0, stream, outp, 4096, 1.0f);
    return;
  }

  P p;
  p.enc    = (const float*)d_in[0];
  p.mels   = (const float*)d_in[2];
  p.w_pre1 = (const float*)d_in[3];
  p.w_pre2 = (const float*)d_in[4];
  p.w_ih1  = (const float*)d_in[5];
  p.w_hh1  = (const float*)d_in[6];
  p.b_ih1  = (const float*)d_in[7];
  p.b_hh1  = (const float*)d_in[8];
  p.w_q    = (const float*)d_in[9];
  p.b_q    = (const float*)d_in[10];
  p.w_enc  = (const float*)d_in[11];
  p.k_loc  = (const float*)d_in[12];
  p.w_loc  = (const float*)d_in[13];
  p.w_e    = (const float*)d_in[14];
  p.w_ih2  = (const float*)d_in[15];
  p.w_hh2  = (const float*)d_in[16];
  p.b_ih2  = (const float*)d_in[17];
  p.b_hh2  = (const float*)d_in[18];
  p.w_mel  = (const float*)d_in[19];
  p.b_mel  = (const float*)d_in[20];
  p.w_stop = (const float*)d_in[21];
  p.b_stop = (const float*)d_in[22];

  float* ws = (float*)d_ws;
  p.encc = ws + OFF_ENCC;
  p.ah   = ws + OFF_AH;    p.ac   = ws + OFF_AC;
  p.dh   = ws + OFF_DH;    p.dc   = ws + OFF_DC;
  p.ctx2 = ws + OFF_CTX2;
  p.wqT  = ws + OFF_WQT;
  p.ka2  = ws + OFF_KA2;   p.kb2  = ws + OFF_KB2;
  p.bias1 = ws + OFF_BIAS1; p.bias2 = ws + OFF_BIAS2;
  p.bar   = (unsigned*)(ws + OFF_BAR);
  unsigned short* xb = (unsigned short*)(ws + OFF_XBUF);
  p.x1hi = xb;             p.x1lo = xb + 57344;
  p.x2hi = xb + 114688;    p.x2lo = xb + 196608;
  p.xs16 = (unsigned short*)(ws + OFF_XS16);
  unsigned short* wpb = (unsigned short*)(ws + OFF_WP);
  p.wp1  = wpb;            p.wp2  = wpb + 7340032;

  p.out_mel  = outp;
  p.out_stop = outp + 1536000;
  p.out_attn = outp + 1555200;

  hipMemsetAsync((void*)(ws + ZERO_BEG), 0, (size_t)ZERO_CNT * 4, stream);
  hipLaunchKernelGGL(k_prenet, dim3(768), dim3(256), 0, stream, p);
  hipLaunchKernelGGL(k_encc,   dim3(1024), dim3(256), 0, stream, p);
  hipLaunchKernelGGL(k_small,  dim3(512), dim3(256), 0, stream, p);
  hipLaunchKernelGGL(k_packw,  dim3(2048), dim3(256), 0, stream, p);

  void* args[] = { &p };
  hipError_t err = hipLaunchCooperativeKernel((void*)k_decoder, dim3(256), dim3(512), args, 0, stream);
  if (err != hipSuccess){
    hipLaunchKernelGGL(k_sentinel, dim3(16), dim3(256), 0, stream, outp, 4096, 4.0f);
  }
}

// Round 8
// 89418.427 us; speedup vs baseline: 1.2695x; 1.2071x over previous
//
#include <hip/hip_runtime.h>
#include <hip/hip_cooperative_groups.h>

namespace cg = cooperative_groups;

typedef __attribute__((ext_vector_type(8))) short bf16x8;
typedef __attribute__((ext_vector_type(4))) float f32x4;

__device__ __forceinline__ float bf2f(unsigned short u){
  union { unsigned int i; float f; } v; v.i = ((unsigned int)u) << 16; return v.f;
}
__device__ __forceinline__ unsigned short f2bf(float f){
  unsigned int u = __float_as_uint(f);
  unsigned int r = (u + 0x7FFFu + ((u >> 16) & 1u)) >> 16;
  return (unsigned short)r;
}
__device__ __forceinline__ float sigm(float x){ return 1.f / (1.f + __expf(-x)); }
__device__ __forceinline__ float ftanh(float x){ float e = __expf(2.f * x); return 1.f - 2.f / (e + 1.f); }

// ---- coherence helpers: L2-bypass (sc0 sc1) accesses for cross-block data ----
__device__ __forceinline__ float ldsys_f(const float* p2){
  return __hip_atomic_load((float*)p2, __ATOMIC_RELAXED, __HIP_MEMORY_SCOPE_SYSTEM);
}
__device__ __forceinline__ float2 ldsys_f2(const float* p2){
  unsigned long long u = __hip_atomic_load((unsigned long long*)p2, __ATOMIC_RELAXED, __HIP_MEMORY_SCOPE_SYSTEM);
  union { unsigned long long u; float2 f; } c; c.u = u; return c.f;
}
__device__ __forceinline__ bf16x8 ldsys_x8(const unsigned short* p2){
  unsigned long long a = __hip_atomic_load((unsigned long long*)p2, __ATOMIC_RELAXED, __HIP_MEMORY_SCOPE_SYSTEM);
  unsigned long long b = __hip_atomic_load((unsigned long long*)(p2 + 4), __ATOMIC_RELAXED, __HIP_MEMORY_SCOPE_SYSTEM);
  union { unsigned long long u[2]; bf16x8 v; } c; c.u[0] = a; c.u[1] = b; return c.v;
}
__device__ __forceinline__ void stsys_f(float* p2, float v){
  __hip_atomic_store(p2, v, __ATOMIC_RELAXED, __HIP_MEMORY_SCOPE_SYSTEM);
}
__device__ __forceinline__ void stsys_u16(unsigned short* p2, unsigned short v){
  __hip_atomic_store(p2, v, __ATOMIC_RELAXED, __HIP_MEMORY_SCOPE_SYSTEM);
}

// ---- fence-free grid barrier: no wbl2, no inv. sc-stores are already at LLC when the
// block arrives (s_waitcnt(0)); readers use ldsys_* bypass loads. ----
__device__ __forceinline__ void gbar(unsigned* cnt, unsigned tgt){
  __builtin_amdgcn_s_waitcnt(0);
  __syncthreads();
  if (threadIdx.x == 0){
    __hip_atomic_fetch_add(cnt, 1u, __ATOMIC_RELAXED, __HIP_MEMORY_SCOPE_SYSTEM);
    while (__hip_atomic_load(cnt, __ATOMIC_RELAXED, __HIP_MEMORY_SCOPE_SYSTEM) < tgt)
      __builtin_amdgcn_s_sleep(2);
  }
  __syncthreads();
}

// ---------------- workspace layout (float offsets); total 14,407,936 fl = 57.63 MB ----------------
#define OFF_ENCC    0           // 32*512*128
#define OFF_AH      2097152     // 2*32*1024
#define OFF_AC      2162688     // 32*1024
#define OFF_DH      2195456     // 2*32*1024
#define OFF_DC      2260992     // 32*1024
#define OFF_CTX2    2293760     // 2*32*512 (double-buffered ctx)
#define OFF_WQT     2342912     // 131072 fl (transposed/blocked w_q)
#define OFF_KA2     2473984     // 3968 fl
#define OFF_KB2     2477952     // 3968 fl
#define OFF_BAR     2887680     // 256 fl: [0] = barrier arrival counter (zeroed every launch)
#define OFF_XBUF    2887936     // ushort region: x1hi/x1lo (57344 each), x2hi/x2lo (81920 each) -> 139264 fl
#define OFF_BIAS1   3029248     // 4096
#define OFF_BIAS2   3033344     // 4096
#define OFF_XS16    3037440     // ushort region: 600*32*256 = 4,915,200 ush -> 2,457,600 fl
#define OFF_WP      5495040     // ushort region: wp1 7,340,032 + wp2 10,485,760 ush -> 8,912,896 fl
#define TOTAL_FL    14407936
#define ZERO_BEG    2097152
#define ZERO_CNT    930048      // floats: AH .. XBUF end (covers OFF_BAR)

struct P {
  const float *enc, *mels, *w_pre1, *w_pre2;
  const float *w_ih1, *w_hh1, *b_ih1, *b_hh1;
  const float *w_q, *b_q, *w_enc, *k_loc, *w_loc, *w_e;
  const float *w_ih2, *w_hh2, *b_ih2, *b_hh2;
  const float *w_mel, *b_mel, *w_stop, *b_stop;
  float *encc;
  float *ah, *ac, *dh, *dc, *ctx2;
  float *wqT, *ka2, *kb2, *bias1, *bias2;
  unsigned short *xs16, *x1hi, *x1lo, *x2hi, *x2lo, *wp1, *wp2;
  float *out_mel, *out_stop, *out_attn;
  unsigned *bar;
};

__global__ void __launch_bounds__(256) k_sentinel(float* out, int n, float v){
  int i = blockIdx.x * 256 + threadIdx.x;
  if (i < n) out[i] = v;
}

// ---------------- setup: fused prenet (whole sequence, teacher-forced) ----------------
__global__ void __launch_bounds__(256) k_prenet(P p){
  __shared__ float in0[2000];   // 25 x 80
  __shared__ float h1[6400];    // 25 x 256
  const int b = blockIdx.x / 24, c = blockIdx.x % 24;
  const int j = threadIdx.x;
  for (int i = j; i < 2000; i += 256){
    const int tt = i / 80, k = i % 80;
    const int t = c * 25 + tt;
    in0[i] = (t == 0) ? 0.f : p.mels[(b * 600 + t - 1) * 80 + k];
  }
  __syncthreads();
  for (int tt = 0; tt < 25; ++tt){
    float acc = 0.f;
    const float* wr = p.w_pre1 + j * 80;
    const float* xr = in0 + tt * 80;
    for (int k = 0; k < 80; ++k) acc += xr[k] * wr[k];
    h1[tt * 256 + j] = fmaxf(acc, 0.f);
  }
  __syncthreads();
  for (int tt = 0; tt < 25; ++tt){
    float acc = 0.f;
    const float* wr = p.w_pre2 + j * 256;
    const float* xr = h1 + tt * 256;
    for (int k = 0; k < 256; k += 4){
      float4 x4 = *(const float4*)(xr + k); float4 w4 = *(const float4*)(wr + k);
      acc += x4.x * w4.x + x4.y * w4.y + x4.z * w4.z + x4.w * w4.w;
    }
    p.xs16[((c * 25 + tt) * 32 + b) * 256 + j] = f2bf(fmaxf(acc, 0.f));
  }
}

// ---------------- setup: enc_cache = enc @ w_enc^T  (fp32) ----------------
__global__ void __launch_bounds__(256) k_encc(P p){
  __shared__ float ex[8192];   // 16 x 512
  const int b = blockIdx.x >> 5, sc = blockIdx.x & 31;
  const int tid = threadIdx.x;
  for (int i = tid; i < 8192; i += 256){
    const int ss = i >> 9, k = i & 511;
    ex[i] = p.enc[((b * 512) + sc * 16 + ss) * 512 + k];
  }
  __syncthreads();
  const int a = tid & 127, sh = tid >> 7;
  const float* wr = p.w_enc + a * 512;
  for (int s8 = 0; s8 < 8; ++s8){
    const int ss = sh * 8 + s8;
    const float* xr = ex + ss * 512;
    float acc = 0.f;
    for (int k = 0; k < 512; k += 4){
      float4 x4 = *(const float4*)(xr + k); float4 w4 = *(const float4*)(wr + k);
      acc += x4.x * w4.x + x4.y * w4.y + x4.z * w4.z + x4.w * w4.w;
    }
    p.encc[((b * 512) + sc * 16 + ss) * 128 + a] = acc;
  }
}

// ---------------- setup: fused biases, KA2/KB2 = w_loc @ k_loc, blocked-transposed w_q ----------------
__global__ void __launch_bounds__(256) k_small(P p){
  const int i = blockIdx.x * 256 + threadIdx.x;
  if (i < 4096){
    p.bias1[i] = p.b_ih1[i] + p.b_hh1[i];
    p.bias2[i] = p.b_ih2[i] + p.b_hh2[i];
  }
  if (i < 3968){
    const int a = i / 31, dk = i % 31;
    float sa = 0.f, sb = 0.f;
    for (int f = 0; f < 32; ++f){
      const float wl = p.w_loc[a * 32 + f];
      sa += wl * p.k_loc[(f * 2 + 0) * 31 + dk];
      sb += wl * p.k_loc[(f * 2 + 1) * 31 + dk];
    }
    p.ka2[i] = sa; p.kb2[i] = sb;
  }
  if (i < 131072){
    // wqT[tid][k'] with tid=(kq*128+a): thread-contiguous 256-fl rows
    const int row = i >> 8, k2 = i & 255;
    const int a = row & 127, kq = row >> 7;
    p.wqT[i] = p.w_q[a * 1024 + kq * 256 + k2];
  }
}

// ---------------- setup: pack LSTM weights (fp32 -> bf16) into MFMA B-fragment order ----------------
__global__ void __launch_bounds__(256) k_packw(P p){
  const int stride = gridDim.x * 256;
  for (int i = blockIdx.x * 256 + threadIdx.x; i < 7340032; i += stride){
    const int j = i & 7, rest = i >> 3;
    const int lane = rest & 63, t2 = rest >> 6;
    const int kc = t2 % 56, nt = t2 / 56;
    const int np = nt * 16 + (lane & 15);
    const int k = kc * 32 + (lane >> 4) * 8 + j;
    const int row = (np & 3) * 1024 + (np >> 2);
    p.wp1[i] = f2bf((k < 768) ? p.w_ih1[row * 768 + k] : p.w_hh1[row * 1024 + (k - 768)]);
  }
  for (int i = blockIdx.x * 256 + threadIdx.x; i < 10485760; i += stride){
    const int j = i & 7, rest = i >> 3;
    const int lane = rest & 63, t2 = rest >> 6;
    const int kc = t2 % 80, nt = t2 / 80;
    const int np = nt * 16 + (lane & 15);
    const int k = kc * 32 + (lane >> 4) * 8 + j;
    const int row = (np & 3) * 1024 + (np >> 2);
    p.wp2[i] = f2bf((k < 1536) ? p.w_ih2[row * 1536 + k] : p.w_hh2[row * 1024 + (k - 1536)]);
  }
}

// ---------------- persistent decoder: 256 blocks x 512 threads, 2 fence-free barriers per step ----------------
// LDS: s_w 139264 + scratch 16384 + awp/cump 4352 + e 2048 + q 512 = 162,560 B <= 160 KiB
// NEW (r8): ah[bb]/dh[bb]/ctx[bb] staged into s_scratch[1024..3584) once per block per step via
// bypass loads; q-dot / out-proj / repack read the LDS copy (wave-broadcast) instead of issuing
// ~150 MB/step of redundant per-lane LLC round-trips.
__global__ void __attribute__((amdgpu_flat_work_group_size(512,512), amdgpu_waves_per_eu(2,2))) k_decoder(P p){
  const int blk = blockIdx.x;
  const int tid = threadIdx.x;

  __shared__ __align__(16) unsigned short s_w[69632];  // wp1 slice [0..28672) + wp2 slice [28672..69632)
  __shared__ __align__(16) float s_scratch[4096];
  __shared__ __align__(16) float s_awp[544];           // 16-zero pad each side of aw[512]
  __shared__ __align__(16) float s_cump[544];
  __shared__ float s_e[512];
  __shared__ float s_q[128];

  const int nt = blk;                 // N-tile for phase M (weights LDS-resident, order free)
  const int bb = blk & 31, xx = blk >> 5;

  // ---- one-time: weights -> LDS; aw/cum (incl. BOTH halo pads) zero ----
  {
    const uint4* s1 = (const uint4*)(p.wp1 + nt * 28672);
    uint4* d = (uint4*)s_w;
    for (int i = tid; i < 3584; i += 512) d[i] = s1[i];
    const uint4* s2 = (const uint4*)(p.wp2 + nt * 40960);
    for (int i = tid; i < 5120; i += 512) d[3584 + i] = s2[i];
    for (int i = tid; i < 544; i += 512){ s_awp[i] = 0.f; s_cump[i] = 0.f; }
  }
  const int aC = tid & 127, slC = tid >> 7;
  // ---- one-time: KA2/KB2 rows + w_e into registers ----
  float ka[31], kb[31];
  {
    const float* kap = p.ka2 + aC * 31;
    const float* kbp = p.kb2 + aC * 31;
    #pragma unroll
    for (int dk = 0; dk < 31; ++dk){ ka[dk] = kap[dk]; kb[dk] = kbp[dk]; }
  }
  const float wea = p.w_e[aC];
  // ---- one-time: enc ctx-slice -> 64 PERMANENT registers (asm pin defeats rematerialization) ----
  float er[64];
  {
    const int s4 = tid >> 6, dl = tid & 63;
    const float* ep = p.enc + ((bb * 512) + s4 * 64) * 512 + xx * 64 + dl;
    #pragma unroll
    for (int ss = 0; ss < 64; ++ss) er[ss] = ep[ss * 512];
    #pragma unroll
    for (int ss = 0; ss < 64; ++ss) asm volatile("" : "+v"(er[ss]));
  }
  __syncthreads();

  unsigned tgt = 0;
  for (int t = 0; t <= 600; ++t){
    const int pn = (t + 1) & 1;

    // ===== Phase M: LSTM1(t) [waves 0-3] and LSTM2(t-1) [waves 4-7], MFMA, weights from LDS =====
    {
      const bool is2 = (tid >= 256);
      const int tt = tid & 255;
      const int w = tt >> 6, lane = tt & 63;
      const int mt = w >> 1, kh = w & 1;
      const int col = lane & 15, q4 = lane >> 4;
      const bool active = is2 ? (t > 0) : (t < 600);
      f32x4 acc; acc.x = 0.f; acc.y = 0.f; acc.z = 0.f; acc.w = 0.f;
      if (active){
        const int m = mt * 16 + col;
        if (!is2){
          const unsigned short* wlp = s_w + lane * 8;
          const unsigned short* xh = p.x1hi + m * 1792 + q4 * 8;
          const unsigned short* xl = p.x1lo + m * 1792 + q4 * 8;
          int kc0 = kh * 28;
          if (kh == 0){
            const unsigned short* xs = p.xs16 + (t * 32 + m) * 256 + q4 * 8;   // static: normal loads
            #pragma unroll
            for (int kc = 0; kc < 8; ++kc){
              bf16x8 a0 = *(const bf16x8*)(xs + kc * 32);
              bf16x8 bw = *(const bf16x8*)(wlp + kc * 512);
              acc = __builtin_amdgcn_mfma_f32_16x16x32_bf16(a0, bw, acc, 0, 0, 0);
            }
            kc0 = 8;
          }
          const int kcEnd = kh * 28 + 28;
          for (int kc = kc0; kc < kcEnd; ++kc){
            bf16x8 a0 = ldsys_x8(xh + kc * 32);
            bf16x8 a1 = ldsys_x8(xl + kc * 32);
            bf16x8 bw = *(const bf16x8*)(wlp + kc * 512);
            acc = __builtin_amdgcn_mfma_f32_16x16x32_bf16(a0, bw, acc, 0, 0, 0);
            acc = __builtin_amdgcn_mfma_f32_16x16x32_bf16(a1, bw, acc, 0, 0, 0);
          }
        } else {
          const unsigned short* wlp = s_w + 28672 + lane * 8;
          const unsigned short* xh = p.x2hi + m * 2560 + q4 * 8;
          const unsigned short* xl = p.x2lo + m * 2560 + q4 * 8;
          const int kcBeg = kh * 40, kcEnd = kcBeg + 40;
          for (int kc = kcBeg; kc < kcEnd; ++kc){
            bf16x8 a0 = ldsys_x8(xh + kc * 32);
            bf16x8 a1 = ldsys_x8(xl + kc * 32);
            bf16x8 bw = *(const bf16x8*)(wlp + kc * 512);
            acc = __builtin_amdgcn_mfma_f32_16x16x32_bf16(a0, bw, acc, 0, 0, 0);
            acc = __builtin_amdgcn_mfma_f32_16x16x32_bf16(a1, bw, acc, 0, 0, 0);
          }
        }
      }
      float* red = s_scratch + (is2 ? 512 : 0);
      if (active && kh == 1){
        red[mt * 256 + lane * 4 + 0] = acc.x;
        red[mt * 256 + lane * 4 + 1] = acc.y;
        red[mt * 256 + lane * 4 + 2] = acc.z;
        red[mt * 256 + lane * 4 + 3] = acc.w;
      }
      __syncthreads();
      if (active && kh == 0){
        acc.x += red[mt * 256 + lane * 4 + 0];
        acc.y += red[mt * 256 + lane * 4 + 1];
        acc.z += red[mt * 256 + lane * 4 + 2];
        acc.w += red[mt * 256 + lane * 4 + 3];
        float vi[4], vf[4], vg[4], vo[4];
        #pragma unroll
        for (int r = 0; r < 4; ++r){
          float a = (r == 0) ? acc.x : (r == 1) ? acc.y : (r == 2) ? acc.z : acc.w;
          float b1 = __shfl_xor(a, 1);
          float b2 = __shfl_xor(a, 2);
          float b3 = __shfl_xor(b1, 2);
          vi[r] = a; vf[r] = b1; vg[r] = b2; vo[r] = b3;
        }
        if ((col & 3) == 0){
          const int u = nt * 4 + (col >> 2);
          const float* bias = is2 ? p.bias2 : p.bias1;
          const float bi = bias[u], bfv = bias[1024 + u], bg = bias[2048 + u], bo = bias[3072 + u];
          float* cbuf = is2 ? p.dc : p.ac;     // block-private: normal load/store, L2-warm
          float* hbuf = (is2 ? p.dh : p.ah) + pn * 32768;   // cross-block: sc-stores to LLC
          #pragma unroll
          for (int r = 0; r < 4; ++r){
            const int br = mt * 16 + q4 * 4 + r;
            float c_ = sigm(vf[r] + bfv) * cbuf[br * 1024 + u] + sigm(vi[r] + bi) * ftanh(vg[r] + bg);
            cbuf[br * 1024 + u] = c_;
            stsys_f(hbuf + br * 1024 + u, sigm(vo[r] + bo) * ftanh(c_));
          }
        }
      }
    }
    tgt += 256; gbar(p.bar, tgt);

    // ===== Phase ATTN (block-local; per block: bb row, xx d-chunk) =====

    // stage ah(t)[bb], dh(t-1)[bb], ctx(t-1)[bb] -> LDS once (bypass loads, unique bytes only);
    // all subsequent q-dot / out-proj / repack reads are LDS broadcasts.
    {
      const float* ahv = p.ah + pn * 32768 + bb * 1024;
      const float* dhv = p.dh + pn * 32768 + bb * 1024;
      const float* ctxv = p.ctx2 + pn * 16384 + bb * 512;
      float2 a2 = ldsys_f2(ahv + tid * 2);
      float2 d2 = ldsys_f2(dhv + tid * 2);
      s_scratch[1024 + tid * 2] = a2.x; s_scratch[1024 + tid * 2 + 1] = a2.y;
      s_scratch[2048 + tid * 2] = d2.x; s_scratch[2048 + tid * 2 + 1] = d2.y;
      s_scratch[3072 + tid] = ldsys_f(ctxv + tid);
    }
    __syncthreads();
    const float* s_ah = s_scratch + 1024;
    const float* s_dh = s_scratch + 2048;
    const float* s_ctx = s_scratch + 3072;

    // out-proj(t-1): spread across the 8 xx blocks (10 mel rows each); stop on xx==0
    if (t > 0 && tid < 22 && (tid < 20 || xx == 0)){
      const int pidx = tid >> 1, hf = tid & 1;
      const bool isMel = (pidx < 10);
      const int m2 = xx * 10 + pidx;
      const float* wr = isMel ? (p.w_mel + m2 * 1536 + hf * 768) : (p.w_stop + hf * 768);
      float s = 0.f;
      if (hf == 0){
        for (int k = 0; k < 768; k += 4){
          float4 x4 = *(const float4*)(s_dh + k); float4 w4 = *(const float4*)(wr + k);
          s += x4.x * w4.x + x4.y * w4.y + x4.z * w4.z + x4.w * w4.w;
        }
      } else {
        for (int k = 0; k < 256; k += 4){
          float4 x4 = *(const float4*)(s_dh + 768 + k); float4 w4 = *(const float4*)(wr + k);
          s += x4.x * w4.x + x4.y * w4.y + x4.z * w4.z + x4.w * w4.w;
        }
        for (int k = 0; k < 512; k += 4){
          float4 x4 = *(const float4*)(s_ctx + k); float4 w4 = *(const float4*)(wr + 256 + k);
          s += x4.x * w4.x + x4.y * w4.y + x4.z * w4.z + x4.w * w4.w;
        }
      }
      s += __shfl_xor(s, 1);
      if (hf == 0){
        if (isMel) p.out_mel[(bb * 600 + (t - 1)) * 80 + m2] = s + p.b_mel[m2];
        else       p.out_stop[bb * 600 + (t - 1)] = s + p.b_stop[0];
      }
    }

    if (t < 600){
      // repack ah(t)/dh(t-1) -> x1/x2 (this block's 384-slot share), reads from LDS, sc-stores
      if (tid < 384){
        const int kk = xx * 384 + tid;
        float v; unsigned short *hb, *lb; int slot;
        if (kk < 1024){ v = s_ah[kk]; hb = p.x1hi; lb = p.x1lo; slot = bb * 1792 + 768 + kk; }
        else if (kk < 2048){ const int k2 = kk - 1024; v = s_ah[k2]; hb = p.x2hi; lb = p.x2lo; slot = bb * 2560 + k2; }
        else { const int k2 = kk - 2048; v = s_dh[k2]; hb = p.x2hi; lb = p.x2lo; slot = bb * 2560 + 1536 + k2; }
        const unsigned short h = f2bf(v);
        stsys_u16(hb + slot, h); stsys_u16(lb + slot, f2bf(v - bf2f(h)));
      }
      // q(t) redundant per block: thread (aC, slC) quarter-dot; ah from LDS (broadcast), wqT L2-warm
      {
        const float* wv = p.wqT + tid * 256;
        const float* av = s_ah + slC * 256;
        float s = 0.f;
        for (int k = 0; k < 256; k += 4){
          float4 x4 = *(const float4*)(av + k); float4 w4 = *(const float4*)(wv + k);
          s += x4.x * w4.x + x4.y * w4.y + x4.z * w4.z + x4.w * w4.w;
        }
        s_scratch[tid] = s;
      }
      __syncthreads();
      if (tid < 128)
        s_q[tid] = s_scratch[tid] + s_scratch[128 + tid] + s_scratch[256 + tid] + s_scratch[384 + tid] + p.b_q[tid];
      __syncthreads();
      const float qa = s_q[aC];

      // e[s] for ALL 512 s (redundant across the 8 xx blocks): 16 chunks of 32 rows,
      // chunk order rotated by xx; encc loads double-buffered (prefetch cc+1 during cc).
      // encc is static -> normal loads, L2-resident across steps (never invalidated).
      int ch = (xx * 2) & 15;
      float ec[8];
      {
        const float* eb = p.encc + (bb * 512 + ch * 32 + slC * 8) * 128 + aC;
        #pragma unroll
        for (int si = 0; si < 8; ++si) ec[si] = eb[si * 128];
      }
      for (int cc = 0; cc < 16; ++cc){
        const int chn = (cc + 1 + xx * 2) & 15;
        float ecn[8];
        if (cc < 15){
          const float* eb = p.encc + (bb * 512 + chn * 32 + slC * 8) * 128 + aC;
          #pragma unroll
          for (int si = 0; si < 8; ++si) ecn[si] = eb[si * 128];
        }
        float vv[8];
        {
          float va[40];
          const float* awb = s_awp + ch * 32 + slC * 8;    // 16B-aligned
          #pragma unroll
          for (int w4i = 0; w4i < 10; ++w4i){
            float4 t4 = *(const float4*)(awb + w4i * 4);
            va[w4i*4+0] = t4.x; va[w4i*4+1] = t4.y; va[w4i*4+2] = t4.z; va[w4i*4+3] = t4.w;
          }
          #pragma unroll
          for (int si = 0; si < 8; ++si){
            float v = qa + ec[si];
            #pragma unroll
            for (int dk = 0; dk < 31; ++dk) v += ka[dk] * va[si + dk + 1];
            vv[si] = v;
          }
        }
        {
          float vc[40];
          const float* cub = s_cump + ch * 32 + slC * 8;
          #pragma unroll
          for (int w4i = 0; w4i < 10; ++w4i){
            float4 u4 = *(const float4*)(cub + w4i * 4);
            vc[w4i*4+0] = u4.x; vc[w4i*4+1] = u4.y; vc[w4i*4+2] = u4.z; vc[w4i*4+3] = u4.w;
          }
          #pragma unroll
          for (int si = 0; si < 8; ++si){
            float v = vv[si];
            #pragma unroll
            for (int dk = 0; dk < 31; ++dk) v += kb[dk] * vc[si + dk + 1];
            s_scratch[(slC * 8 + si) * 128 + aC] = ftanh(v) * wea;
          }
        }
        __syncthreads();
        if (tid < 256){
          const int i2 = tid >> 3, p8 = tid & 7;
          float ssum = 0.f;
          const float* rr = s_scratch + i2 * 128 + p8 * 16;
          #pragma unroll
          for (int k = 0; k < 16; ++k) ssum += rr[k];
          ssum += __shfl_xor(ssum, 1); ssum += __shfl_xor(ssum, 2); ssum += __shfl_xor(ssum, 4);
          if (p8 == 0) s_e[ch * 32 + i2] = ssum;
        }
        __syncthreads();
        ch = chn;
        #pragma unroll
        for (int si = 0; si < 8; ++si) ec[si] = ecn[si];
      }

      // block-local softmax -> aw, cum
      {
        const int wid = tid >> 6, lane = tid & 63;
        const float v = s_e[tid];
        float mx = v;
        #pragma unroll
        for (int off = 32; off >= 1; off >>= 1) mx = fmaxf(mx, __shfl_xor(mx, off));
        if (lane == 0) s_scratch[wid] = mx;
        __syncthreads();
        mx = s_scratch[0];
        #pragma unroll
        for (int j = 1; j < 8; ++j) mx = fmaxf(mx, s_scratch[j]);
        const float wv2 = __expf(v - mx);
        float ps = wv2;
        #pragma unroll
        for (int off = 32; off >= 1; off >>= 1) ps += __shfl_xor(ps, off);
        if (lane == 0) s_scratch[8 + wid] = ps;
        __syncthreads();
        ps = 0.f;
        #pragma unroll
        for (int j = 0; j < 8; ++j) ps += s_scratch[8 + j];
        const float inv = 1.f / ps;
        const float awv = wv2 * inv;
        s_awp[16 + tid] = awv;
        s_cump[16 + tid] += awv;
        if (xx == (bb & 7)) p.out_attn[(bb * 600 + t) * 512 + tid] = awv;
      }
      __syncthreads();

      // ctx d-chunk (this block's 64 d values) from the permanently-pinned enc registers
      {
        const int s4 = tid >> 6;
        const float* awb2 = s_awp + 16 + s4 * 64;
        float accc = 0.f;
        #pragma unroll
        for (int ss4 = 0; ss4 < 16; ++ss4){
          const float4 a4 = *(const float4*)(awb2 + ss4 * 4);
          accc += a4.x * er[ss4 * 4 + 0] + a4.y * er[ss4 * 4 + 1]
                + a4.z * er[ss4 * 4 + 2] + a4.w * er[ss4 * 4 + 3];
        }
        s_scratch[tid] = accc;
        __syncthreads();
        if (tid < 64){
          float r0 = 0.f;
          #pragma unroll
          for (int j2 = 0; j2 < 8; ++j2) r0 += s_scratch[j2 * 64 + tid];
          const int d2 = xx * 64 + tid;
          stsys_f(p.ctx2 + (1 - pn) * 16384 + bb * 512 + d2, r0);
          const unsigned short h = f2bf(r0);
          const unsigned short l = f2bf(r0 - bf2f(h));
          stsys_u16(p.x1hi + bb * 1792 + 256 + d2, h);  stsys_u16(p.x1lo + bb * 1792 + 256 + d2, l);
          stsys_u16(p.x2hi + bb * 2560 + 1024 + d2, h); stsys_u16(p.x2lo + bb * 2560 + 1024 + d2, l);
        }
      }
    }

    if (t == 600) break;
    tgt += 256; gbar(p.bar, tgt);
  }
}

extern "C" void kernel_launch(void* const* d_in, const int* in_sizes, int n_in,
                              void* d_out, int out_size, void* d_ws, size_t ws_size,
                              hipStream_t stream){
  float* outp = (float*)d_out;

  if (ws_size < (size_t)TOTAL_FL * 4){
    hipLaunchKernelGGL(k_sentinel, dim3(16), dim3(256), 0, stream, outp, 4096, 1.0f);
    return;
  }

  P p;
  p.enc    = (const float*)d_in[0];
  p.mels   = (const float*)d_in[2];
  p.w_pre1 = (const float*)d_in[3];
  p.w_pre2 = (const float*)d_in[4];
  p.w_ih1  = (const float*)d_in[5];
  p.w_hh1  = (const float*)d_in[6];
  p.b_ih1  = (const float*)d_in[7];
  p.b_hh1  = (const float*)d_in[8];
  p.w_q    = (const float*)d_in[9];
  p.b_q    = (const float*)d_in[10];
  p.w_enc  = (const float*)d_in[11];
  p.k_loc  = (const float*)d_in[12];
  p.w_loc  = (const float*)d_in[13];
  p.w_e    = (const float*)d_in[14];
  p.w_ih2  = (const float*)d_in[15];
  p.w_hh2  = (const float*)d_in[16];
  p.b_ih2  = (const float*)d_in[17];
  p.b_hh2  = (const float*)d_in[18];
  p.w_mel  = (const float*)d_in[19];
  p.b_mel  = (const float*)d_in[20];
  p.w_stop = (const float*)d_in[21];
  p.b_stop = (const float*)d_in[22];

  float* ws = (float*)d_ws;
  p.encc = ws + OFF_ENCC;
  p.ah   = ws + OFF_AH;    p.ac   = ws + OFF_AC;
  p.dh   = ws + OFF_DH;    p.dc   = ws + OFF_DC;
  p.ctx2 = ws + OFF_CTX2;
  p.wqT  = ws + OFF_WQT;
  p.ka2  = ws + OFF_KA2;   p.kb2  = ws + OFF_KB2;
  p.bias1 = ws + OFF_BIAS1; p.bias2 = ws + OFF_BIAS2;
  p.bar   = (unsigned*)(ws + OFF_BAR);
  unsigned short* xb = (unsigned short*)(ws + OFF_XBUF);
  p.x1hi = xb;             p.x1lo = xb + 57344;
  p.x2hi = xb + 114688;    p.x2lo = xb + 196608;
  p.xs16 = (unsigned short*)(ws + OFF_XS16);
  unsigned short* wpb = (unsigned short*)(ws + OFF_WP);
  p.wp1  = wpb;            p.wp2  = wpb + 7340032;

  p.out_mel  = outp;
  p.out_stop = outp + 1536000;
  p.out_attn = outp + 1555200;

  hipMemsetAsync((void*)(ws + ZERO_BEG), 0, (size_t)ZERO_CNT * 4, stream);
  hipLaunchKernelGGL(k_prenet, dim3(768), dim3(256), 0, stream, p);
  hipLaunchKernelGGL(k_encc,   dim3(1024), dim3(256), 0, stream, p);
  hipLaunchKernelGGL(k_small,  dim3(512), dim3(256), 0, stream, p);
  hipLaunchKernelGGL(k_packw,  dim3(2048), dim3(256), 0, stream, p);

  void* args[] = { &p };
  hipError_t err = hipLaunchCooperativeKernel((void*)k_decoder, dim3(256), dim3(512), args, 0, stream);
  if (err != hipSuccess){
    hipLaunchKernelGGL(k_sentinel, dim3(16), dim3(256), 0, stream, outp, 4096, 4.0f);
  }
}

// Round 9
// 84336.365 us; speedup vs baseline: 1.3460x; 1.0603x over previous
//
#include <hip/hip_runtime.h>
#include <hip/hip_cooperative_groups.h>

namespace cg = cooperative_groups;

typedef __attribute__((ext_vector_type(8))) short bf16x8;
typedef __attribute__((ext_vector_type(4))) float f32x4;

__device__ __forceinline__ float bf2f(unsigned short u){
  union { unsigned int i; float f; } v; v.i = ((unsigned int)u) << 16; return v.f;
}
__device__ __forceinline__ unsigned short f2bf(float f){
  unsigned int u = __float_as_uint(f);
  unsigned int r = (u + 0x7FFFu + ((u >> 16) & 1u)) >> 16;
  return (unsigned short)r;
}
__device__ __forceinline__ float sigm(float x){ return 1.f / (1.f + __expf(-x)); }
__device__ __forceinline__ float ftanh(float x){ float e = __expf(2.f * x); return 1.f - 2.f / (e + 1.f); }

// ---- coherence helpers: L2-bypass (sc0 sc1) accesses for cross-block data ----
__device__ __forceinline__ float ldsys_f(const float* p2){
  return __hip_atomic_load((float*)p2, __ATOMIC_RELAXED, __HIP_MEMORY_SCOPE_SYSTEM);
}
__device__ __forceinline__ float2 ldsys_f2(const float* p2){
  unsigned long long u = __hip_atomic_load((unsigned long long*)p2, __ATOMIC_RELAXED, __HIP_MEMORY_SCOPE_SYSTEM);
  union { unsigned long long u; float2 f; } c; c.u = u; return c.f;
}
__device__ __forceinline__ bf16x8 ldsys_x8(const unsigned short* p2){
  unsigned long long a = __hip_atomic_load((unsigned long long*)p2, __ATOMIC_RELAXED, __HIP_MEMORY_SCOPE_SYSTEM);
  unsigned long long b = __hip_atomic_load((unsigned long long*)(p2 + 4), __ATOMIC_RELAXED, __HIP_MEMORY_SCOPE_SYSTEM);
  union { unsigned long long u[2]; bf16x8 v; } c; c.u[0] = a; c.u[1] = b; return c.v;
}
__device__ __forceinline__ void stsys_f(float* p2, float v){
  __hip_atomic_store(p2, v, __ATOMIC_RELAXED, __HIP_MEMORY_SCOPE_SYSTEM);
}
__device__ __forceinline__ void stsys_u16(unsigned short* p2, unsigned short v){
  __hip_atomic_store(p2, v, __ATOMIC_RELAXED, __HIP_MEMORY_SCOPE_SYSTEM);
}

// ---- fence-free TWO-LEVEL tree barrier (no wbl2, no inv; generation-counted) ----
// Flat 256-way fetch_add + 256-way poll on one LLC line serializes; split into
// 8 group lines (32 arrivers each) -> 1 root line (8 arrivers) -> 1 release line
// (single writer, 256 read-only pollers). All counters zeroed at launch; k = call index.
__device__ __forceinline__ void gbar(unsigned* bt, unsigned k, int blk){
  __builtin_amdgcn_s_waitcnt(0);     // this thread's sc-stores have reached the LLC
  __syncthreads();                   // whole block done + drained
  if (threadIdx.x == 0){
    unsigned* grp  = bt + (blk >> 5) * 32;   // 8 lines, 128 B apart
    unsigned* root = bt + 256;
    unsigned* rel  = bt + 288;
    unsigned n = __hip_atomic_fetch_add(grp, 1u, __ATOMIC_RELAXED, __HIP_MEMORY_SCOPE_SYSTEM);
    if (n == 32u * k - 1u){                  // last of this group's k-th wave
      unsigned r = __hip_atomic_fetch_add(root, 1u, __ATOMIC_RELAXED, __HIP_MEMORY_SCOPE_SYSTEM);
      if (r == 8u * k - 1u)                  // global last -> publish release
        __hip_atomic_store(rel, k, __ATOMIC_RELAXED, __HIP_MEMORY_SCOPE_SYSTEM);
    }
    while (__hip_atomic_load(rel, __ATOMIC_RELAXED, __HIP_MEMORY_SCOPE_SYSTEM) < k)
      __builtin_amdgcn_s_sleep(2);
  }
  __syncthreads();
}

// ---------------- workspace layout (float offsets); total 14,407,936 fl = 57.63 MB ----------------
#define OFF_ENCC    0           // 32*512*128
#define OFF_AH      2097152     // 2*32*1024
#define OFF_AC      2162688     // 32*1024
#define OFF_DH      2195456     // 2*32*1024
#define OFF_DC      2260992     // 32*1024
#define OFF_CTX2    2293760     // 2*32*512 (double-buffered ctx)
#define OFF_WQT     2342912     // 131072 fl (transposed/blocked w_q)
#define OFF_KA2     2473984     // 3968 fl
#define OFF_KB2     2477952     // 3968 fl
#define OFF_BARTREE 2482176     // 320 fl: grp[8]@g*32, root@256, rel@288 (zeroed every launch)
#define OFF_XBUF    2887936     // ushort region: x1c 114688 ush + x2c 163840 ush = 139264 fl
#define OFF_BIAS1   3029248     // 4096
#define OFF_BIAS2   3033344     // 4096
#define OFF_XS16    3037440     // ushort region: 600*32*256 = 4,915,200 ush -> 2,457,600 fl
#define OFF_WP      5495040     // ushort region: wp1 7,340,032 + wp2 10,485,760 ush -> 8,912,896 fl
#define TOTAL_FL    14407936
#define ZERO_BEG    2097152
#define ZERO_CNT    930048      // floats: AH .. XBUF end (covers BARTREE)

// X layout (interleaved hi/lo): element eidx of row m ->
//   hi at rowbase + (eidx>>3)*16 + (eidx&7), lo at +8   (ush units)
// x1c rowstride 3584 ush (1792 elems), x2c rowstride 5120 ush (2560 elems).

struct P {
  const float *enc, *mels, *w_pre1, *w_pre2;
  const float *w_ih1, *w_hh1, *b_ih1, *b_hh1;
  const float *w_q, *b_q, *w_enc, *k_loc, *w_loc, *w_e;
  const float *w_ih2, *w_hh2, *b_ih2, *b_hh2;
  const float *w_mel, *b_mel, *w_stop, *b_stop;
  float *encc;
  float *ah, *ac, *dh, *dc, *ctx2;
  float *wqT, *ka2, *kb2, *bias1, *bias2;
  unsigned short *xs16, *x1c, *x2c, *wp1, *wp2;
  float *out_mel, *out_stop, *out_attn;
  unsigned *bar;
};

__global__ void __launch_bounds__(256) k_sentinel(float* out, int n, float v){
  int i = blockIdx.x * 256 + threadIdx.x;
  if (i < n) out[i] = v;
}

// ---------------- setup: fused prenet (whole sequence, teacher-forced) ----------------
__global__ void __launch_bounds__(256) k_prenet(P p){
  __shared__ float in0[2000];   // 25 x 80
  __shared__ float h1[6400];    // 25 x 256
  const int b = blockIdx.x / 24, c = blockIdx.x % 24;
  const int j = threadIdx.x;
  for (int i = j; i < 2000; i += 256){
    const int tt = i / 80, k = i % 80;
    const int t = c * 25 + tt;
    in0[i] = (t == 0) ? 0.f : p.mels[(b * 600 + t - 1) * 80 + k];
  }
  __syncthreads();
  for (int tt = 0; tt < 25; ++tt){
    float acc = 0.f;
    const float* wr = p.w_pre1 + j * 80;
    const float* xr = in0 + tt * 80;
    for (int k = 0; k < 80; ++k) acc += xr[k] * wr[k];
    h1[tt * 256 + j] = fmaxf(acc, 0.f);
  }
  __syncthreads();
  for (int tt = 0; tt < 25; ++tt){
    float acc = 0.f;
    const float* wr = p.w_pre2 + j * 256;
    const float* xr = h1 + tt * 256;
    for (int k = 0; k < 256; k += 4){
      float4 x4 = *(const float4*)(xr + k); float4 w4 = *(const float4*)(wr + k);
      acc += x4.x * w4.x + x4.y * w4.y + x4.z * w4.z + x4.w * w4.w;
    }
    p.xs16[((c * 25 + tt) * 32 + b) * 256 + j] = f2bf(fmaxf(acc, 0.f));
  }
}

// ---------------- setup: enc_cache = enc @ w_enc^T  (fp32) ----------------
__global__ void __launch_bounds__(256) k_encc(P p){
  __shared__ float ex[8192];   // 16 x 512
  const int b = blockIdx.x >> 5, sc = blockIdx.x & 31;
  const int tid = threadIdx.x;
  for (int i = tid; i < 8192; i += 256){
    const int ss = i >> 9, k = i & 511;
    ex[i] = p.enc[((b * 512) + sc * 16 + ss) * 512 + k];
  }
  __syncthreads();
  const int a = tid & 127, sh = tid >> 7;
  const float* wr = p.w_enc + a * 512;
  for (int s8 = 0; s8 < 8; ++s8){
    const int ss = sh * 8 + s8;
    const float* xr = ex + ss * 512;
    float acc = 0.f;
    for (int k = 0; k < 512; k += 4){
      float4 x4 = *(const float4*)(xr + k); float4 w4 = *(const float4*)(wr + k);
      acc += x4.x * w4.x + x4.y * w4.y + x4.z * w4.z + x4.w * w4.w;
    }
    p.encc[((b * 512) + sc * 16 + ss) * 128 + a] = acc;
  }
}

// ---------------- setup: fused biases, KA2/KB2 = w_loc @ k_loc, blocked-transposed w_q ----------------
__global__ void __launch_bounds__(256) k_small(P p){
  const int i = blockIdx.x * 256 + threadIdx.x;
  if (i < 4096){
    p.bias1[i] = p.b_ih1[i] + p.b_hh1[i];
    p.bias2[i] = p.b_ih2[i] + p.b_hh2[i];
  }
  if (i < 3968){
    const int a = i / 31, dk = i % 31;
    float sa = 0.f, sb = 0.f;
    for (int f = 0; f < 32; ++f){
      const float wl = p.w_loc[a * 32 + f];
      sa += wl * p.k_loc[(f * 2 + 0) * 31 + dk];
      sb += wl * p.k_loc[(f * 2 + 1) * 31 + dk];
    }
    p.ka2[i] = sa; p.kb2[i] = sb;
  }
  if (i < 131072){
    // wqT[tid][k'] with tid=(kq*128+a): thread-contiguous 256-fl rows
    const int row = i >> 8, k2 = i & 255;
    const int a = row & 127, kq = row >> 7;
    p.wqT[i] = p.w_q[a * 1024 + kq * 256 + k2];
  }
}

// ---------------- setup: pack LSTM weights (fp32 -> bf16) into MFMA B-fragment order ----------------
__global__ void __launch_bounds__(256) k_packw(P p){
  const int stride = gridDim.x * 256;
  for (int i = blockIdx.x * 256 + threadIdx.x; i < 7340032; i += stride){
    const int j = i & 7, rest = i >> 3;
    const int lane = rest & 63, t2 = rest >> 6;
    const int kc = t2 % 56, nt = t2 / 56;
    const int np = nt * 16 + (lane & 15);
    const int k = kc * 32 + (lane >> 4) * 8 + j;
    const int row = (np & 3) * 1024 + (np >> 2);
    p.wp1[i] = f2bf((k < 768) ? p.w_ih1[row * 768 + k] : p.w_hh1[row * 1024 + (k - 768)]);
  }
  for (int i = blockIdx.x * 256 + threadIdx.x; i < 10485760; i += stride){
    const int j = i & 7, rest = i >> 3;
    const int lane = rest & 63, t2 = rest >> 6;
    const int kc = t2 % 80, nt = t2 / 80;
    const int np = nt * 16 + (lane & 15);
    const int k = kc * 32 + (lane >> 4) * 8 + j;
    const int row = (np & 3) * 1024 + (np >> 2);
    p.wp2[i] = f2bf((k < 1536) ? p.w_ih2[row * 1536 + k] : p.w_hh2[row * 1024 + (k - 1536)]);
  }
}

// ---------------- persistent decoder: 256 blocks x 512 threads, 2 tree-barriers per step ----------------
// LDS: s_w 139264 + scratch 16384 + awp/cump 4352 + e 2048 + q 512 = 162,560 B <= 160 KiB
__global__ void __attribute__((amdgpu_flat_work_group_size(512,512), amdgpu_waves_per_eu(2,2))) k_decoder(P p){
  const int blk = blockIdx.x;
  const int tid = threadIdx.x;

  __shared__ __align__(16) unsigned short s_w[69632];  // wp1 slice [0..28672) + wp2 slice [28672..69632)
  __shared__ __align__(16) float s_scratch[4096];
  __shared__ __align__(16) float s_awp[544];           // 16-zero pad each side of aw[512]
  __shared__ __align__(16) float s_cump[544];
  __shared__ float s_e[512];
  __shared__ float s_q[128];

  const int nt = blk;                 // N-tile for phase M (weights LDS-resident, order free)
  const int bb = blk & 31, xx = blk >> 5;

  // ---- one-time: weights -> LDS; aw/cum (incl. BOTH halo pads) zero ----
  {
    const uint4* s1 = (const uint4*)(p.wp1 + nt * 28672);
    uint4* d = (uint4*)s_w;
    for (int i = tid; i < 3584; i += 512) d[i] = s1[i];
    const uint4* s2 = (const uint4*)(p.wp2 + nt * 40960);
    for (int i = tid; i < 5120; i += 512) d[3584 + i] = s2[i];
    for (int i = tid; i < 544; i += 512){ s_awp[i] = 0.f; s_cump[i] = 0.f; }
  }
  const int aC = tid & 127, slC = tid >> 7;
  // ---- one-time: KA2/KB2 rows + w_e into registers ----
  float ka[31], kb[31];
  {
    const float* kap = p.ka2 + aC * 31;
    const float* kbp = p.kb2 + aC * 31;
    #pragma unroll
    for (int dk = 0; dk < 31; ++dk){ ka[dk] = kap[dk]; kb[dk] = kbp[dk]; }
  }
  const float wea = p.w_e[aC];
  // ---- one-time: enc ctx-slice -> 64 PERMANENT registers (asm pin defeats rematerialization) ----
  float er[64];
  {
    const int s4 = tid >> 6, dl = tid & 63;
    const float* ep = p.enc + ((bb * 512) + s4 * 64) * 512 + xx * 64 + dl;
    #pragma unroll
    for (int ss = 0; ss < 64; ++ss) er[ss] = ep[ss * 512];
    #pragma unroll
    for (int ss = 0; ss < 64; ++ss) asm volatile("" : "+v"(er[ss]));
  }
  __syncthreads();

  unsigned bk = 0;
  for (int t = 0; t <= 600; ++t){
    const int pn = (t + 1) & 1;

    // ===== Phase M: LSTM1(t) [waves 0-3] and LSTM2(t-1) [waves 4-7], MFMA, weights from LDS =====
    {
      const bool is2 = (tid >= 256);
      const int tt = tid & 255;
      const int w = tt >> 6, lane = tt & 63;
      const int mt = w >> 1, kh = w & 1;
      const int col = lane & 15, q4 = lane >> 4;
      const bool active = is2 ? (t > 0) : (t < 600);
      f32x4 acc; acc.x = 0.f; acc.y = 0.f; acc.z = 0.f; acc.w = 0.f;
      if (active){
        const int m = mt * 16 + col;
        if (!is2){
          const unsigned short* wlp = s_w + lane * 8;
          const unsigned short* xp = p.x1c + m * 3584 + q4 * 16;   // interleaved hi|lo, 32 B/kc
          int kc0 = kh * 28;
          if (kh == 0){
            const unsigned short* xs = p.xs16 + (t * 32 + m) * 256 + q4 * 8;   // static: normal loads
            #pragma unroll
            for (int kc = 0; kc < 8; ++kc){
              bf16x8 a0 = *(const bf16x8*)(xs + kc * 32);
              bf16x8 bw = *(const bf16x8*)(wlp + kc * 512);
              acc = __builtin_amdgcn_mfma_f32_16x16x32_bf16(a0, bw, acc, 0, 0, 0);
            }
            kc0 = 8;
          }
          const int kcEnd = kh * 28 + 28;
          for (int kc = kc0; kc < kcEnd; ++kc){
            bf16x8 a0 = ldsys_x8(xp + kc * 64);
            bf16x8 a1 = ldsys_x8(xp + kc * 64 + 8);
            bf16x8 bw = *(const bf16x8*)(wlp + kc * 512);
            acc = __builtin_amdgcn_mfma_f32_16x16x32_bf16(a0, bw, acc, 0, 0, 0);
            acc = __builtin_amdgcn_mfma_f32_16x16x32_bf16(a1, bw, acc, 0, 0, 0);
          }
        } else {
          const unsigned short* wlp = s_w + 28672 + lane * 8;
          const unsigned short* xp = p.x2c + m * 5120 + q4 * 16;
          const int kcBeg = kh * 40, kcEnd = kcBeg + 40;
          for (int kc = kcBeg; kc < kcEnd; ++kc){
            bf16x8 a0 = ldsys_x8(xp + kc * 64);
            bf16x8 a1 = ldsys_x8(xp + kc * 64 + 8);
            bf16x8 bw = *(const bf16x8*)(wlp + kc * 512);
            acc = __builtin_amdgcn_mfma_f32_16x16x32_bf16(a0, bw, acc, 0, 0, 0);
            acc = __builtin_amdgcn_mfma_f32_16x16x32_bf16(a1, bw, acc, 0, 0, 0);
          }
        }
      }
      float* red = s_scratch + (is2 ? 512 : 0);
      if (active && kh == 1){
        red[mt * 256 + lane * 4 + 0] = acc.x;
        red[mt * 256 + lane * 4 + 1] = acc.y;
        red[mt * 256 + lane * 4 + 2] = acc.z;
        red[mt * 256 + lane * 4 + 3] = acc.w;
      }
      __syncthreads();
      if (active && kh == 0){
        acc.x += red[mt * 256 + lane * 4 + 0];
        acc.y += red[mt * 256 + lane * 4 + 1];
        acc.z += red[mt * 256 + lane * 4 + 2];
        acc.w += red[mt * 256 + lane * 4 + 3];
        float vi[4], vf[4], vg[4], vo[4];
        #pragma unroll
        for (int r = 0; r < 4; ++r){
          float a = (r == 0) ? acc.x : (r == 1) ? acc.y : (r == 2) ? acc.z : acc.w;
          float b1 = __shfl_xor(a, 1);
          float b2 = __shfl_xor(a, 2);
          float b3 = __shfl_xor(b1, 2);
          vi[r] = a; vf[r] = b1; vg[r] = b2; vo[r] = b3;
        }
        if ((col & 3) == 0){
          const int u = nt * 4 + (col >> 2);
          const float* bias = is2 ? p.bias2 : p.bias1;
          const float bi = bias[u], bfv = bias[1024 + u], bg = bias[2048 + u], bo = bias[3072 + u];
          float* cbuf = is2 ? p.dc : p.ac;     // block-private: normal load/store, L2-warm
          float* hbuf = (is2 ? p.dh : p.ah) + pn * 32768;   // cross-block: sc-stores to LLC
          #pragma unroll
          for (int r = 0; r < 4; ++r){
            const int br = mt * 16 + q4 * 4 + r;
            float c_ = sigm(vf[r] + bfv) * cbuf[br * 1024 + u] + sigm(vi[r] + bi) * ftanh(vg[r] + bg);
            cbuf[br * 1024 + u] = c_;
            stsys_f(hbuf + br * 1024 + u, sigm(vo[r] + bo) * ftanh(c_));
          }
        }
      }
    }
    ++bk; gbar(p.bar, bk, blk);

    // ===== Phase ATTN (block-local; per block: bb row, xx d-chunk) =====

    // stage ah(t)[bb], dh(t-1)[bb], ctx(t-1)[bb] -> LDS once (bypass loads, unique bytes only)
    {
      const float* ahv = p.ah + pn * 32768 + bb * 1024;
      const float* dhv = p.dh + pn * 32768 + bb * 1024;
      const float* ctxv = p.ctx2 + pn * 16384 + bb * 512;
      float2 a2 = ldsys_f2(ahv + tid * 2);
      float2 d2 = ldsys_f2(dhv + tid * 2);
      s_scratch[1024 + tid * 2] = a2.x; s_scratch[1024 + tid * 2 + 1] = a2.y;
      s_scratch[2048 + tid * 2] = d2.x; s_scratch[2048 + tid * 2 + 1] = d2.y;
      s_scratch[3072 + tid] = ldsys_f(ctxv + tid);
    }
    __syncthreads();
    const float* s_ah = s_scratch + 1024;
    const float* s_dh = s_scratch + 2048;
    const float* s_ctx = s_scratch + 3072;

    // out-proj(t-1): spread across the 8 xx blocks (10 mel rows each); stop on xx==0
    if (t > 0 && tid < 22 && (tid < 20 || xx == 0)){
      const int pidx = tid >> 1, hf = tid & 1;
      const bool isMel = (pidx < 10);
      const int m2 = xx * 10 + pidx;
      const float* wr = isMel ? (p.w_mel + m2 * 1536 + hf * 768) : (p.w_stop + hf * 768);
      float s = 0.f;
      if (hf == 0){
        for (int k = 0; k < 768; k += 4){
          float4 x4 = *(const float4*)(s_dh + k); float4 w4 = *(const float4*)(wr + k);
          s += x4.x * w4.x + x4.y * w4.y + x4.z * w4.z + x4.w * w4.w;
        }
      } else {
        for (int k = 0; k < 256; k += 4){
          float4 x4 = *(const float4*)(s_dh + 768 + k); float4 w4 = *(const float4*)(wr + k);
          s += x4.x * w4.x + x4.y * w4.y + x4.z * w4.z + x4.w * w4.w;
        }
        for (int k = 0; k < 512; k += 4){
          float4 x4 = *(const float4*)(s_ctx + k); float4 w4 = *(const float4*)(wr + 256 + k);
          s += x4.x * w4.x + x4.y * w4.y + x4.z * w4.z + x4.w * w4.w;
        }
      }
      s += __shfl_xor(s, 1);
      if (hf == 0){
        if (isMel) p.out_mel[(bb * 600 + (t - 1)) * 80 + m2] = s + p.b_mel[m2];
        else       p.out_stop[bb * 600 + (t - 1)] = s + p.b_stop[0];
      }
    }

    if (t < 600){
      // repack ah(t)/dh(t-1) -> x1/x2 (this block's 384-element share), LDS reads, sc-stores
      if (tid < 384){
        const int kk = xx * 384 + tid;
        float v; unsigned short *cb; int eidx, rowb;
        if (kk < 1024){ v = s_ah[kk]; cb = p.x1c; rowb = bb * 3584; eidx = 768 + kk; }
        else if (kk < 2048){ const int k2 = kk - 1024; v = s_ah[k2]; cb = p.x2c; rowb = bb * 5120; eidx = k2; }
        else { const int k2 = kk - 2048; v = s_dh[k2]; cb = p.x2c; rowb = bb * 5120; eidx = 1536 + k2; }
        const unsigned short h = f2bf(v);
        unsigned short* dst = cb + rowb + (eidx >> 3) * 16 + (eidx & 7);
        stsys_u16(dst, h); stsys_u16(dst + 8, f2bf(v - bf2f(h)));
      }
      // q(t) redundant per block: thread (aC, slC) quarter-dot; ah from LDS (broadcast), wqT L2-warm
      {
        const float* wv = p.wqT + tid * 256;
        const float* av = s_ah + slC * 256;
        float s = 0.f;
        for (int k = 0; k < 256; k += 4){
          float4 x4 = *(const float4*)(av + k); float4 w4 = *(const float4*)(wv + k);
          s += x4.x * w4.x + x4.y * w4.y + x4.z * w4.z + x4.w * w4.w;
        }
        s_scratch[tid] = s;
      }
      __syncthreads();
      if (tid < 128)
        s_q[tid] = s_scratch[tid] + s_scratch[128 + tid] + s_scratch[256 + tid] + s_scratch[384 + tid] + p.b_q[tid];
      __syncthreads();
      const float qa = s_q[aC];

      // e[s] for ALL 512 s (redundant across the 8 xx blocks): 16 chunks of 32 rows,
      // chunk order rotated by xx; encc loads double-buffered (prefetch cc+1 during cc).
      int ch = (xx * 2) & 15;
      float ec[8];
      {
        const float* eb = p.encc + (bb * 512 + ch * 32 + slC * 8) * 128 + aC;
        #pragma unroll
        for (int si = 0; si < 8; ++si) ec[si] = eb[si * 128];
      }
      for (int cc = 0; cc < 16; ++cc){
        const int chn = (cc + 1 + xx * 2) & 15;
        float ecn[8];
        if (cc < 15){
          const float* eb = p.encc + (bb * 512 + chn * 32 + slC * 8) * 128 + aC;
          #pragma unroll
          for (int si = 0; si < 8; ++si) ecn[si] = eb[si * 128];
        }
        float vv[8];
        {
          float va[40];
          const float* awb = s_awp + ch * 32 + slC * 8;    // 16B-aligned
          #pragma unroll
          for (int w4i = 0; w4i < 10; ++w4i){
            float4 t4 = *(const float4*)(awb + w4i * 4);
            va[w4i*4+0] = t4.x; va[w4i*4+1] = t4.y; va[w4i*4+2] = t4.z; va[w4i*4+3] = t4.w;
          }
          #pragma unroll
          for (int si = 0; si < 8; ++si){
            float v = qa + ec[si];
            #pragma unroll
            for (int dk = 0; dk < 31; ++dk) v += ka[dk] * va[si + dk + 1];
            vv[si] = v;
          }
        }
        {
          float vc[40];
          const float* cub = s_cump + ch * 32 + slC * 8;
          #pragma unroll
          for (int w4i = 0; w4i < 10; ++w4i){
            float4 u4 = *(const float4*)(cub + w4i * 4);
            vc[w4i*4+0] = u4.x; vc[w4i*4+1] = u4.y; vc[w4i*4+2] = u4.z; vc[w4i*4+3] = u4.w;
          }
          #pragma unroll
          for (int si = 0; si < 8; ++si){
            float v = vv[si];
            #pragma unroll
            for (int dk = 0; dk < 31; ++dk) v += kb[dk] * vc[si + dk + 1];
            s_scratch[(slC * 8 + si) * 128 + aC] = ftanh(v) * wea;
          }
        }
        __syncthreads();
        if (tid < 256){
          const int i2 = tid >> 3, p8 = tid & 7;
          float ssum = 0.f;
          const float* rr = s_scratch + i2 * 128 + p8 * 16;
          #pragma unroll
          for (int k = 0; k < 16; ++k) ssum += rr[k];
          ssum += __shfl_xor(ssum, 1); ssum += __shfl_xor(ssum, 2); ssum += __shfl_xor(ssum, 4);
          if (p8 == 0) s_e[ch * 32 + i2] = ssum;
        }
        __syncthreads();
        ch = chn;
        #pragma unroll
        for (int si = 0; si < 8; ++si) ec[si] = ecn[si];
      }

      // block-local softmax -> aw, cum
      {
        const int wid = tid >> 6, lane = tid & 63;
        const float v = s_e[tid];
        float mx = v;
        #pragma unroll
        for (int off = 32; off >= 1; off >>= 1) mx = fmaxf(mx, __shfl_xor(mx, off));
        if (lane == 0) s_scratch[wid] = mx;
        __syncthreads();
        mx = s_scratch[0];
        #pragma unroll
        for (int j = 1; j < 8; ++j) mx = fmaxf(mx, s_scratch[j]);
        const float wv2 = __expf(v - mx);
        float ps = wv2;
        #pragma unroll
        for (int off = 32; off >= 1; off >>= 1) ps += __shfl_xor(ps, off);
        if (lane == 0) s_scratch[8 + wid] = ps;
        __syncthreads();
        ps = 0.f;
        #pragma unroll
        for (int j = 0; j < 8; ++j) ps += s_scratch[8 + j];
        const float inv = 1.f / ps;
        const float awv = wv2 * inv;
        s_awp[16 + tid] = awv;
        s_cump[16 + tid] += awv;
        if (xx == (bb & 7)) p.out_attn[(bb * 600 + t) * 512 + tid] = awv;
      }
      __syncthreads();

      // ctx d-chunk (this block's 64 d values) from the permanently-pinned enc registers
      {
        const int s4 = tid >> 6;
        const float* awb2 = s_awp + 16 + s4 * 64;
        float accc = 0.f;
        #pragma unroll
        for (int ss4 = 0; ss4 < 16; ++ss4){
          const float4 a4 = *(const float4*)(awb2 + ss4 * 4);
          accc += a4.x * er[ss4 * 4 + 0] + a4.y * er[ss4 * 4 + 1]
                + a4.z * er[ss4 * 4 + 2] + a4.w * er[ss4 * 4 + 3];
        }
        s_scratch[tid] = accc;
        __syncthreads();
        if (tid < 64){
          float r0 = 0.f;
          #pragma unroll
          for (int j2 = 0; j2 < 8; ++j2) r0 += s_scratch[j2 * 64 + tid];
          const int d2 = xx * 64 + tid;
          stsys_f(p.ctx2 + (1 - pn) * 16384 + bb * 512 + d2, r0);
          const unsigned short h = f2bf(r0);
          const unsigned short l = f2bf(r0 - bf2f(h));
          // x1 eidx = 256 + d2 ; x2 eidx = 1024 + d2 (interleaved hi|lo)
          unsigned short* d1 = p.x1c + bb * 3584 + ((256 + d2) >> 3) * 16 + ((256 + d2) & 7);
          unsigned short* dx = p.x2c + bb * 5120 + ((1024 + d2) >> 3) * 16 + ((1024 + d2) & 7);
          stsys_u16(d1, h); stsys_u16(d1 + 8, l);
          stsys_u16(dx, h); stsys_u16(dx + 8, l);
        }
      }
    }

    if (t == 600) break;
    ++bk; gbar(p.bar, bk, blk);
  }
}

extern "C" void kernel_launch(void* const* d_in, const int* in_sizes, int n_in,
                              void* d_out, int out_size, void* d_ws, size_t ws_size,
                              hipStream_t stream){
  float* outp = (float*)d_out;

  if (ws_size < (size_t)TOTAL_FL * 4){
    hipLaunchKernelGGL(k_sentinel, dim3(16), dim3(256), 0, stream, outp, 4096, 1.0f);
    return;
  }

  P p;
  p.enc    = (const float*)d_in[0];
  p.mels   = (const float*)d_in[2];
  p.w_pre1 = (const float*)d_in[3];
  p.w_pre2 = (const float*)d_in[4];
  p.w_ih1  = (const float*)d_in[5];
  p.w_hh1  = (const float*)d_in[6];
  p.b_ih1  = (const float*)d_in[7];
  p.b_hh1  = (const float*)d_in[8];
  p.w_q    = (const float*)d_in[9];
  p.b_q    = (const float*)d_in[10];
  p.w_enc  = (const float*)d_in[11];
  p.k_loc  = (const float*)d_in[12];
  p.w_loc  = (const float*)d_in[13];
  p.w_e    = (const float*)d_in[14];
  p.w_ih2  = (const float*)d_in[15];
  p.w_hh2  = (const float*)d_in[16];
  p.b_ih2  = (const float*)d_in[17];
  p.b_hh2  = (const float*)d_in[18];
  p.w_mel  = (const float*)d_in[19];
  p.b_mel  = (const float*)d_in[20];
  p.w_stop = (const float*)d_in[21];
  p.b_stop = (const float*)d_in[22];

  float* ws = (float*)d_ws;
  p.encc = ws + OFF_ENCC;
  p.ah   = ws + OFF_AH;    p.ac   = ws + OFF_AC;
  p.dh   = ws + OFF_DH;    p.dc   = ws + OFF_DC;
  p.ctx2 = ws + OFF_CTX2;
  p.wqT  = ws + OFF_WQT;
  p.ka2  = ws + OFF_KA2;   p.kb2  = ws + OFF_KB2;
  p.bias1 = ws + OFF_BIAS1; p.bias2 = ws + OFF_BIAS2;
  p.bar   = (unsigned*)(ws + OFF_BARTREE);
  unsigned short* xb = (unsigned short*)(ws + OFF_XBUF);
  p.x1c = xb;              p.x2c = xb + 114688;
  p.xs16 = (unsigned short*)(ws + OFF_XS16);
  unsigned short* wpb = (unsigned short*)(ws + OFF_WP);
  p.wp1  = wpb;            p.wp2  = wpb + 7340032;

  p.out_mel  = outp;
  p.out_stop = outp + 1536000;
  p.out_attn = outp + 1555200;

  hipMemsetAsync((void*)(ws + ZERO_BEG), 0, (size_t)ZERO_CNT * 4, stream);
  hipLaunchKernelGGL(k_prenet, dim3(768), dim3(256), 0, stream, p);
  hipLaunchKernelGGL(k_encc,   dim3(1024), dim3(256), 0, stream, p);
  hipLaunchKernelGGL(k_small,  dim3(512), dim3(256), 0, stream, p);
  hipLaunchKernelGGL(k_packw,  dim3(2048), dim3(256), 0, stream, p);

  void* args[] = { &p };
  hipError_t err = hipLaunchCooperativeKernel((void*)k_decoder, dim3(256), dim3(512), args, 0, stream);
  if (err != hipSuccess){
    hipLaunchKernelGGL(k_sentinel, dim3(16), dim3(256), 0, stream, outp, 4096, 4.0f);
  }
}